// Round 1
// baseline (864.273 us; speedup 1.0000x reference)
//
#include <hip/hip_runtime.h>

#define BN_EPS 1e-5f

// ---------------- CSR build ----------------

__global__ void hist_kernel(const int* __restrict__ dst, int* __restrict__ cnt, int E) {
  int e = blockIdx.x * 256 + threadIdx.x;
  if (e < E) atomicAdd(&cnt[dst[e]], 1);
}

__device__ __forceinline__ int block_exscan256(int v, int tid, int* ws4) {
  __syncthreads();                 // protect ws4 reuse across calls
  int lane = tid & 63, w = tid >> 6;
  int x = v;
  #pragma unroll
  for (int off = 1; off < 64; off <<= 1) {
    int y = __shfl_up(x, off, 64);
    if (lane >= off) x += y;
  }
  if (lane == 63) ws4[w] = x;
  __syncthreads();
  if (tid == 0) {
    int s = 0;
    for (int i = 0; i < 4; ++i) { int t = ws4[i]; ws4[i] = s; s += t; }
  }
  __syncthreads();
  return ws4[w] + x - v;           // exclusive scan of v over the block
}

__global__ void blocksum_kernel(const int* __restrict__ cnt, int* __restrict__ bsum, int N) {
  __shared__ int ws4[4];
  int tid = threadIdx.x;
  int i = blockIdx.x * 256 + tid;
  int v = (i < N) ? cnt[i] : 0;
  #pragma unroll
  for (int off = 32; off > 0; off >>= 1) v += __shfl_down(v, off, 64);
  if ((tid & 63) == 0) ws4[tid >> 6] = v;
  __syncthreads();
  if (tid == 0) bsum[blockIdx.x] = ws4[0] + ws4[1] + ws4[2] + ws4[3];
}

__global__ void scanbsum_kernel(const int* __restrict__ bsum, int* __restrict__ boff,
                                int NB, int* __restrict__ rowptr, int N, int E) {
  __shared__ int ws4[4];
  __shared__ int tot;
  int tid = threadIdx.x;
  int carry = 0;
  for (int base = 0; base < NB; base += 256) {
    int i = base + tid;
    int v = (i < NB) ? bsum[i] : 0;
    int ex = block_exscan256(v, tid, ws4);
    if (i < NB) boff[i] = carry + ex;
    if (tid == 255) tot = ex + v;
    __syncthreads();
    carry += tot;
  }
  if (tid == 0) rowptr[N] = E;
}

__global__ void writerowptr_kernel(const int* __restrict__ cnt, const int* __restrict__ boff,
                                   int* __restrict__ rowptr, int N) {
  __shared__ int ws4[4];
  int tid = threadIdx.x;
  int i = blockIdx.x * 256 + tid;
  int v = (i < N) ? cnt[i] : 0;
  int ex = block_exscan256(v, tid, ws4);
  if (i < N) rowptr[i] = boff[blockIdx.x] + ex;
}

__global__ void fill_kernel(const int* __restrict__ src, const int* __restrict__ dst,
                            const int* __restrict__ rowptr, int* __restrict__ cur,
                            int* __restrict__ col, int E) {
  int e = blockIdx.x * 256 + threadIdx.x;
  if (e < E) {
    int d = dst[e];
    int p = rowptr[d] + atomicAdd(&cur[d], 1);
    col[p] = src[e];
  }
}

__global__ void deginv_kernel(const int* __restrict__ rowptr, float* __restrict__ dinv, int N) {
  int i = blockIdx.x * 256 + threadIdx.x;
  if (i < N) {
    int d = rowptr[i + 1] - rowptr[i];
    dinv[i] = 1.0f / (float)(d > 0 ? d : 1);
  }
}

// ---------------- mean aggregation: one wave per node ----------------

__global__ void agg_kernel(const int* __restrict__ rowptr, const int* __restrict__ col,
                           const float* __restrict__ dinv, const float* __restrict__ h,
                           float* __restrict__ agg, int N) {
  int node = blockIdx.x * 4 + (threadIdx.x >> 6);
  if (node >= N) return;
  int lane = threadIdx.x & 63;
  int beg = rowptr[node], end = rowptr[node + 1];
  float ax = 0.f, ay = 0.f;
  for (int e = beg; e < end; ++e) {
    int s = col[e];
    float2 v = *(const float2*)(h + (size_t)s * 128 + lane * 2);
    ax += v.x; ay += v.y;
  }
  float di = dinv[node];
  *(float2*)(agg + (size_t)node * 128 + lane * 2) = make_float2(ax * di, ay * di);
}

// ---------------- fused GEMM: out = res + relu(bn([A0|A1] @ [B0;B1] + bias)) ----------------
// A is conceptually [N,256]: k<128 from A0, k>=128 from A1 (both row stride lda).
// B is [256,128]: rows 0..127 = B0, rows 128..255 = B1 (row-major 128 cols).
// BM=64, BN=128, BK=32; 256 threads; 4x8 micro-tile per thread.

__global__ __launch_bounds__(256)
void gemm_fused(const float* __restrict__ A0, const float* __restrict__ A1, int lda,
                const float* __restrict__ B0, const float* __restrict__ B1,
                const float* __restrict__ bias,
                const float* __restrict__ gamma, const float* __restrict__ beta,
                const float* __restrict__ mean, const float* __restrict__ var,
                const float* __restrict__ residual, float* __restrict__ out, int N) {
  __shared__ float As[32][68];   // [k][row], pad 68 keeps 16B alignment per row
  __shared__ float Bs[32][128];  // [k][col]

  int tid = threadIdx.x;
  int tx = tid & 15;   // column group: cols tx*4..+3 and 64+tx*4..+3
  int ty = tid >> 4;   // row group: rows ty*4..+3
  int m0 = blockIdx.x * 64;

  float acc[4][8];
  #pragma unroll
  for (int i = 0; i < 4; ++i)
    #pragma unroll
    for (int j = 0; j < 8; ++j) acc[i][j] = 0.f;

  for (int kt = 0; kt < 8; ++kt) {
    const float* Ap = (kt < 4 ? A0 : A1) + (kt & 3) * 32;
    const float* Bp = (kt < 4 ? B0 : B1) + (size_t)(kt & 3) * 32 * 128;
    __syncthreads();
    // stage A tile (transposed into LDS)
    #pragma unroll
    for (int i = 0; i < 2; ++i) {
      int it = tid + i * 256;
      int r = it >> 3;
      int kq = (it & 7) * 4;
      int row = m0 + r;
      float4 v = make_float4(0.f, 0.f, 0.f, 0.f);
      if (row < N) v = *(const float4*)(Ap + (size_t)row * lda + kq);
      As[kq + 0][r] = v.x; As[kq + 1][r] = v.y; As[kq + 2][r] = v.z; As[kq + 3][r] = v.w;
    }
    // stage B tile
    #pragma unroll
    for (int i = 0; i < 4; ++i) {
      int it = tid + i * 256;
      int kr = it >> 5;
      int jq = (it & 31) * 4;
      *(float4*)&Bs[kr][jq] = *(const float4*)(Bp + kr * 128 + jq);
    }
    __syncthreads();
    #pragma unroll
    for (int kk = 0; kk < 32; ++kk) {
      float4 a  = *(const float4*)&As[kk][ty * 4];
      float4 b0 = *(const float4*)&Bs[kk][tx * 4];
      float4 b1 = *(const float4*)&Bs[kk][64 + tx * 4];
      float av[4] = {a.x, a.y, a.z, a.w};
      float bv[8] = {b0.x, b0.y, b0.z, b0.w, b1.x, b1.y, b1.z, b1.w};
      #pragma unroll
      for (int i = 0; i < 4; ++i)
        #pragma unroll
        for (int j = 0; j < 8; ++j)
          acc[i][j] += av[i] * bv[j];
    }
  }

  // epilogue: bias + BN + ReLU + residual
  #pragma unroll
  for (int i = 0; i < 4; ++i) {
    int row = m0 + ty * 4 + i;
    if (row >= N) continue;
    #pragma unroll
    for (int jj = 0; jj < 2; ++jj) {
      int c0 = jj * 64 + tx * 4;
      float4 r4;
      float* rp = &r4.x;
      float4 res = make_float4(0.f, 0.f, 0.f, 0.f);
      if (residual) res = *(const float4*)(residual + (size_t)row * 128 + c0);
      const float* rsp = &res.x;
      #pragma unroll
      for (int j = 0; j < 4; ++j) {
        int c = c0 + j;
        float v = acc[i][jj * 4 + j] + bias[c];
        float sc = gamma[c] * rsqrtf(var[c] + BN_EPS);
        v = (v - mean[c]) * sc + beta[c];
        v = fmaxf(v, 0.f);
        rp[j] = v + rsp[j];
      }
      *(float4*)(out + (size_t)row * 128 + c0) = r4;
    }
  }
}

// ---------------- launch ----------------

extern "C" void kernel_launch(void* const* d_in, const int* in_sizes, int n_in,
                              void* d_out, int out_size, void* d_ws, size_t ws_size,
                              hipStream_t stream) {
  const float* x      = (const float*)d_in[0];
  const int*   eidx   = (const int*)d_in[1];
  const float* W_in   = (const float*)d_in[2];
  const float* b_in   = (const float*)d_in[3];
  const float* bng_in = (const float*)d_in[4];
  const float* bnb_in = (const float*)d_in[5];
  const float* bnm_in = (const float*)d_in[6];
  const float* bnv_in = (const float*)d_in[7];
  const float* Wl     = (const float*)d_in[8];
  const float* bl     = (const float*)d_in[9];
  const float* Wr     = (const float*)d_in[10];
  const float* bng    = (const float*)d_in[11];
  const float* bnb    = (const float*)d_in[12];
  const float* bnm    = (const float*)d_in[13];
  const float* bnv    = (const float*)d_in[14];

  const int N = in_sizes[0] / 256;
  const int E = in_sizes[1] / 2;
  const int NB = (N + 255) / 256;
  const int* src = eidx;
  const int* dst = eidx + E;

  // workspace layout
  char* ws = (char*)d_ws;
  size_t off = 0;
  int* cnt = (int*)(ws + off);      off += (size_t)N * 4;          // also reused as fill cursor
  int* rowptr = (int*)(ws + off);   off += ((size_t)(N + 1) * 4 + 15) & ~(size_t)15;
  int* bsum = (int*)(ws + off);     off += ((size_t)NB * 4 + 15) & ~(size_t)15;
  int* boff = (int*)(ws + off);     off += ((size_t)NB * 4 + 15) & ~(size_t)15;
  int* col = (int*)(ws + off);      off += (size_t)E * 4;
  float* dinv = (float*)(ws + off); off += (size_t)N * 4;
  float* hA = (float*)(ws + off);   off += (size_t)N * 128 * 4;
  float* agg = (float*)(ws + off);  off += (size_t)N * 128 * 4;
  (void)ws_size; (void)n_in; (void)out_size;

  float* hOut = (float*)d_out;

  const int EB = (E + 255) / 256;
  const int GB = (N + 63) / 64;

  // ---- CSR build ----
  hipMemsetAsync(cnt, 0, (size_t)N * 4, stream);
  hist_kernel<<<EB, 256, 0, stream>>>(dst, cnt, E);
  blocksum_kernel<<<NB, 256, 0, stream>>>(cnt, bsum, N);
  scanbsum_kernel<<<1, 256, 0, stream>>>(bsum, boff, NB, rowptr, N, E);
  writerowptr_kernel<<<NB, 256, 0, stream>>>(cnt, boff, rowptr, N);
  hipMemsetAsync(cnt, 0, (size_t)N * 4, stream);
  fill_kernel<<<EB, 256, 0, stream>>>(src, dst, rowptr, cnt, col, E);
  deginv_kernel<<<NB, 256, 0, stream>>>(rowptr, dinv, N);

  // ---- input projection: hA = relu(bn(x @ W_in + b_in)) ----
  gemm_fused<<<GB, 256, 0, stream>>>(x, x + 128, 256,
                                     W_in, W_in + 128 * 128,
                                     b_in, bng_in, bnb_in, bnm_in, bnv_in,
                                     nullptr, hA, N);

  // ---- 3 SAGE layers, ping-pong hA <-> d_out ----
  for (int l = 0; l < 3; ++l) {
    const float* h_in = (l == 1) ? hOut : hA;
    float* h_out = (l == 1) ? hA : hOut;
    agg_kernel<<<(N + 3) / 4, 256, 0, stream>>>(rowptr, col, dinv, h_in, agg, N);
    gemm_fused<<<GB, 256, 0, stream>>>(agg, h_in, 128,
                                       Wl + (size_t)l * 16384, Wr + (size_t)l * 16384,
                                       bl + l * 128,
                                       bng + l * 128, bnb + l * 128, bnm + l * 128, bnv + l * 128,
                                       h_in, h_out, N);
  }
}

// Round 2
// 603.749 us; speedup vs baseline: 1.4315x; 1.4315x over previous
//
#include <hip/hip_runtime.h>

#define BN_EPS 1e-5f

typedef __bf16 bf16x8 __attribute__((ext_vector_type(8)));
typedef float f32x4 __attribute__((ext_vector_type(4)));
typedef unsigned int uint;
typedef unsigned short ushort;

__device__ __forceinline__ ushort f2bf(float f) {
  union { float f; uint u; } v; v.f = f;
  uint r = v.u + 0x7FFF + ((v.u >> 16) & 1);   // RNE
  return (ushort)(r >> 16);
}
__device__ __forceinline__ float bf2f(ushort u) {
  union { uint i; float f; } v; v.i = ((uint)u) << 16; return v.f;
}
__device__ __forceinline__ float bf2f_lo(uint u) {
  union { uint i; float f; } v; v.i = u << 16; return v.f;
}
__device__ __forceinline__ float bf2f_hi(uint u) {
  union { uint i; float f; } v; v.i = u & 0xffff0000u; return v.f;
}
__device__ __forceinline__ uint pack2(float a, float b) {
  return (uint)f2bf(a) | ((uint)f2bf(b) << 16);
}

// ---------------- CSR build ----------------

__global__ void hist_kernel(const int* __restrict__ dst, int* __restrict__ cnt, int E) {
  int e = blockIdx.x * 256 + threadIdx.x;
  if (e < E) atomicAdd(&cnt[dst[e]], 1);
}

__device__ __forceinline__ int block_exscan256(int v, int tid, int* ws4) {
  __syncthreads();
  int lane = tid & 63, w = tid >> 6;
  int x = v;
  #pragma unroll
  for (int off = 1; off < 64; off <<= 1) {
    int y = __shfl_up(x, off, 64);
    if (lane >= off) x += y;
  }
  if (lane == 63) ws4[w] = x;
  __syncthreads();
  if (tid == 0) {
    int s = 0;
    for (int i = 0; i < 4; ++i) { int t = ws4[i]; ws4[i] = s; s += t; }
  }
  __syncthreads();
  return ws4[w] + x - v;
}

__global__ void blocksum_kernel(const int* __restrict__ cnt, int* __restrict__ bsum, int N) {
  __shared__ int ws4[4];
  int tid = threadIdx.x;
  int i = blockIdx.x * 256 + tid;
  int v = (i < N) ? cnt[i] : 0;
  #pragma unroll
  for (int off = 32; off > 0; off >>= 1) v += __shfl_down(v, off, 64);
  if ((tid & 63) == 0) ws4[tid >> 6] = v;
  __syncthreads();
  if (tid == 0) bsum[blockIdx.x] = ws4[0] + ws4[1] + ws4[2] + ws4[3];
}

__global__ void scanbsum_kernel(const int* __restrict__ bsum, int* __restrict__ boff,
                                int NB, int* __restrict__ rowptr, int N, int E) {
  __shared__ int ws4[4];
  __shared__ int tot;
  int tid = threadIdx.x;
  int carry = 0;
  for (int base = 0; base < NB; base += 256) {
    int i = base + tid;
    int v = (i < NB) ? bsum[i] : 0;
    int ex = block_exscan256(v, tid, ws4);
    if (i < NB) boff[i] = carry + ex;
    if (tid == 255) tot = ex + v;
    __syncthreads();
    carry += tot;
  }
  if (tid == 0) rowptr[N] = E;
}

__global__ void writerowptr_kernel(const int* __restrict__ cnt, const int* __restrict__ boff,
                                   int* __restrict__ rowptr, int N) {
  __shared__ int ws4[4];
  int tid = threadIdx.x;
  int i = blockIdx.x * 256 + tid;
  int v = (i < N) ? cnt[i] : 0;
  int ex = block_exscan256(v, tid, ws4);
  if (i < N) rowptr[i] = boff[blockIdx.x] + ex;
}

__global__ void fill_kernel(const int* __restrict__ src, const int* __restrict__ dst,
                            const int* __restrict__ rowptr, int* __restrict__ cur,
                            int* __restrict__ col, int E) {
  int e = blockIdx.x * 256 + threadIdx.x;
  if (e < E) {
    int d = dst[e];
    int p = rowptr[d] + atomicAdd(&cur[d], 1);
    col[p] = src[e];
  }
}

__global__ void deginv_kernel(const int* __restrict__ rowptr, float* __restrict__ dinv, int N) {
  int i = blockIdx.x * 256 + threadIdx.x;
  if (i < N) {
    int d = rowptr[i + 1] - rowptr[i];
    dinv[i] = 1.0f / (float)(d > 0 ? d : 1);
  }
}

// ---------------- weight prep: Bt[n][k] = B[k][n] in bf16 ----------------
// Bt_in: [128][256] from W_in [256][128]
// Bt_l[l]: [128][256]; k<128 -> Wl[l][k][n], k>=128 -> Wr[l][k-128][n]

__global__ void prep_weights(const float* __restrict__ W_in, const float* __restrict__ Wl,
                             const float* __restrict__ Wr,
                             ushort* __restrict__ Bt_in, ushort* __restrict__ Bt_l) {
  int idx = blockIdx.x * 256 + threadIdx.x;
  if (idx < 32768) {
    int n = idx >> 8, k = idx & 255;
    Bt_in[n * 256 + k] = f2bf(W_in[k * 128 + n]);
  }
  if (idx < 98304) {
    int l = idx >> 15;
    int rem = idx & 32767;
    int n = rem >> 8, k = rem & 255;
    float v = (k < 128) ? Wl[l * 16384 + k * 128 + n]
                        : Wr[l * 16384 + (k - 128) * 128 + n];
    Bt_l[(size_t)l * 32768 + n * 256 + k] = f2bf(v);
  }
}

// ---------------- mean aggregation (bf16 h): one wave per node ----------------

__global__ void agg_kernel(const int* __restrict__ rowptr, const int* __restrict__ col,
                           const float* __restrict__ dinv, const ushort* __restrict__ h,
                           ushort* __restrict__ agg, int N) {
  int node = blockIdx.x * 4 + (threadIdx.x >> 6);
  if (node >= N) return;
  int lane = threadIdx.x & 63;
  int beg = rowptr[node], end = rowptr[node + 1];
  float ax = 0.f, ay = 0.f;
  int e = beg;
  for (; e + 1 < end; e += 2) {
    int s0 = col[e], s1 = col[e + 1];
    uint v0 = *(const uint*)(h + (size_t)s0 * 128 + lane * 2);
    uint v1 = *(const uint*)(h + (size_t)s1 * 128 + lane * 2);
    ax += bf2f_lo(v0) + bf2f_lo(v1);
    ay += bf2f_hi(v0) + bf2f_hi(v1);
  }
  if (e < end) {
    uint v0 = *(const uint*)(h + (size_t)col[e] * 128 + lane * 2);
    ax += bf2f_lo(v0);
    ay += bf2f_hi(v0);
  }
  float di = dinv[node];
  *(uint*)(agg + (size_t)node * 128 + lane * 2) = pack2(ax * di, ay * di);
}

// ---------------- MFMA GEMM (layers): out = h_in + relu(bn([agg|h_in] @ Bt^T + bias)) ----
// A0 = agg [N,128] bf16 (k 0..127), A1 = h_in [N,128] bf16 (k 128..255)
// Bt = [128 n][256 k] bf16. BM=128, BN=128, BK=32, 4 waves (2x2), 64x64/wave.

template<bool F32OUT>
__global__ __launch_bounds__(256)
void gemm_layer(const ushort* __restrict__ A0, const ushort* __restrict__ A1,
                const ushort* __restrict__ Bt, const float* __restrict__ bias,
                const float* __restrict__ gamma, const float* __restrict__ beta,
                const float* __restrict__ mean, const float* __restrict__ var,
                const ushort* __restrict__ residual, void* __restrict__ out, int N) {
  __shared__ ushort As[128 * 32];
  __shared__ ushort Bs[128 * 32];
  int tid = threadIdx.x;
  int wave = tid >> 6, lane = tid & 63;
  int wm = wave >> 1, wn = wave & 1;
  int quad = lane >> 4, l16 = lane & 15;
  int m0 = blockIdx.x * 128;

  f32x4 acc[4][4] = {};

  for (int kt = 0; kt < 8; ++kt) {
    const ushort* Ap = (kt < 4 ? A0 : A1) + (kt & 3) * 32;
    __syncthreads();
    #pragma unroll
    for (int i = 0; i < 2; ++i) {
      int it = tid + i * 256;          // 512 segments of 8 bf16
      int r = it >> 2;
      int ko = (it & 3) * 8;
      uint4 v = make_uint4(0, 0, 0, 0);
      if (m0 + r < N) v = *(const uint4*)(Ap + (size_t)(m0 + r) * 128 + ko);
      *(uint4*)&As[r * 32 + ko] = v;
    }
    #pragma unroll
    for (int i = 0; i < 2; ++i) {
      int it = tid + i * 256;
      int n = it >> 2;
      int ko = (it & 3) * 8;
      *(uint4*)&Bs[n * 32 + ko] = *(const uint4*)(Bt + n * 256 + kt * 32 + ko);
    }
    __syncthreads();
    bf16x8 af[4], bfr[4];
    #pragma unroll
    for (int t = 0; t < 4; ++t) {
      af[t]  = *(bf16x8*)&As[(wm * 64 + t * 16 + l16) * 32 + quad * 8];
      bfr[t] = *(bf16x8*)&Bs[(wn * 64 + t * 16 + l16) * 32 + quad * 8];
    }
    #pragma unroll
    for (int mt = 0; mt < 4; ++mt)
      #pragma unroll
      for (int nt = 0; nt < 4; ++nt)
        acc[mt][nt] = __builtin_amdgcn_mfma_f32_16x16x32_bf16(af[mt], bfr[nt], acc[mt][nt], 0, 0, 0);
  }

  #pragma unroll
  for (int nt = 0; nt < 4; ++nt) {
    int c = wn * 64 + nt * 16 + l16;
    float sc = gamma[c] * rsqrtf(var[c] + BN_EPS);
    float sh = beta[c] - mean[c] * sc;
    float bi = bias[c];
    #pragma unroll
    for (int mt = 0; mt < 4; ++mt) {
      #pragma unroll
      for (int r = 0; r < 4; ++r) {
        int row = m0 + wm * 64 + mt * 16 + quad * 4 + r;
        if (row < N) {
          float v = acc[mt][nt][r] + bi;
          v = fmaxf(v * sc + sh, 0.f);
          v += bf2f(residual[(size_t)row * 128 + c]);
          if (F32OUT) ((float*)out)[(size_t)row * 128 + c] = v;
          else        ((ushort*)out)[(size_t)row * 128 + c] = f2bf(v);
        }
      }
    }
  }
}

// ---------------- MFMA GEMM (input proj): h = relu(bn(x @ W_in + b)), x fp32 ------

__global__ __launch_bounds__(256)
void gemm_in(const float* __restrict__ A, const ushort* __restrict__ Bt,
             const float* __restrict__ bias,
             const float* __restrict__ gamma, const float* __restrict__ beta,
             const float* __restrict__ mean, const float* __restrict__ var,
             ushort* __restrict__ out, int N) {
  __shared__ ushort As[128 * 32];
  __shared__ ushort Bs[128 * 32];
  int tid = threadIdx.x;
  int wave = tid >> 6, lane = tid & 63;
  int wm = wave >> 1, wn = wave & 1;
  int quad = lane >> 4, l16 = lane & 15;
  int m0 = blockIdx.x * 128;

  f32x4 acc[4][4] = {};

  for (int kt = 0; kt < 8; ++kt) {
    __syncthreads();
    {
      int r = tid >> 1;
      int ko = (tid & 1) * 16;
      const float* ap = A + (size_t)(m0 + r) * 256 + kt * 32 + ko;
      float4 v0 = make_float4(0, 0, 0, 0), v1 = v0, v2 = v0, v3 = v0;
      if (m0 + r < N) {
        v0 = *(const float4*)(ap + 0);
        v1 = *(const float4*)(ap + 4);
        v2 = *(const float4*)(ap + 8);
        v3 = *(const float4*)(ap + 12);
      }
      uint4 p0, p1;
      p0.x = pack2(v0.x, v0.y); p0.y = pack2(v0.z, v0.w);
      p0.z = pack2(v1.x, v1.y); p0.w = pack2(v1.z, v1.w);
      p1.x = pack2(v2.x, v2.y); p1.y = pack2(v2.z, v2.w);
      p1.z = pack2(v3.x, v3.y); p1.w = pack2(v3.z, v3.w);
      *(uint4*)&As[r * 32 + ko] = p0;
      *(uint4*)&As[r * 32 + ko + 8] = p1;
    }
    #pragma unroll
    for (int i = 0; i < 2; ++i) {
      int it = tid + i * 256;
      int n = it >> 2;
      int ko = (it & 3) * 8;
      *(uint4*)&Bs[n * 32 + ko] = *(const uint4*)(Bt + n * 256 + kt * 32 + ko);
    }
    __syncthreads();
    bf16x8 af[4], bfr[4];
    #pragma unroll
    for (int t = 0; t < 4; ++t) {
      af[t]  = *(bf16x8*)&As[(wm * 64 + t * 16 + l16) * 32 + quad * 8];
      bfr[t] = *(bf16x8*)&Bs[(wn * 64 + t * 16 + l16) * 32 + quad * 8];
    }
    #pragma unroll
    for (int mt = 0; mt < 4; ++mt)
      #pragma unroll
      for (int nt = 0; nt < 4; ++nt)
        acc[mt][nt] = __builtin_amdgcn_mfma_f32_16x16x32_bf16(af[mt], bfr[nt], acc[mt][nt], 0, 0, 0);
  }

  #pragma unroll
  for (int nt = 0; nt < 4; ++nt) {
    int c = wn * 64 + nt * 16 + l16;
    float sc = gamma[c] * rsqrtf(var[c] + BN_EPS);
    float sh = beta[c] - mean[c] * sc;
    float bi = bias[c];
    #pragma unroll
    for (int mt = 0; mt < 4; ++mt) {
      #pragma unroll
      for (int r = 0; r < 4; ++r) {
        int row = m0 + wm * 64 + mt * 16 + quad * 4 + r;
        if (row < N) {
          float v = acc[mt][nt][r] + bi;
          v = fmaxf(v * sc + sh, 0.f);
          out[(size_t)row * 128 + c] = f2bf(v);
        }
      }
    }
  }
}

// ---------------- launch ----------------

extern "C" void kernel_launch(void* const* d_in, const int* in_sizes, int n_in,
                              void* d_out, int out_size, void* d_ws, size_t ws_size,
                              hipStream_t stream) {
  const float* x      = (const float*)d_in[0];
  const int*   eidx   = (const int*)d_in[1];
  const float* W_in   = (const float*)d_in[2];
  const float* b_in   = (const float*)d_in[3];
  const float* bng_in = (const float*)d_in[4];
  const float* bnb_in = (const float*)d_in[5];
  const float* bnm_in = (const float*)d_in[6];
  const float* bnv_in = (const float*)d_in[7];
  const float* Wl     = (const float*)d_in[8];
  const float* bl     = (const float*)d_in[9];
  const float* Wr     = (const float*)d_in[10];
  const float* bng    = (const float*)d_in[11];
  const float* bnb    = (const float*)d_in[12];
  const float* bnm    = (const float*)d_in[13];
  const float* bnv    = (const float*)d_in[14];

  const int N = in_sizes[0] / 256;
  const int E = in_sizes[1] / 2;
  const int NB = (N + 255) / 256;
  const int* src = eidx;
  const int* dst = eidx + E;

  char* ws = (char*)d_ws;
  size_t off = 0;
  auto alloc = [&](size_t bytes) {
    void* p = ws + off;
    off = (off + bytes + 255) & ~(size_t)255;
    return p;
  };
  int* cnt      = (int*)alloc((size_t)N * 4);
  int* rowptr   = (int*)alloc((size_t)(N + 1) * 4);
  int* bsum     = (int*)alloc((size_t)NB * 4);
  int* boff     = (int*)alloc((size_t)NB * 4);
  int* col      = (int*)alloc((size_t)E * 4);
  float* dinv   = (float*)alloc((size_t)N * 4);
  ushort* Bt_in = (ushort*)alloc(128 * 256 * 2);
  ushort* Bt_l  = (ushort*)alloc(3 * 128 * 256 * 2);
  ushort* hA    = (ushort*)alloc((size_t)N * 128 * 2);
  ushort* hB    = (ushort*)alloc((size_t)N * 128 * 2);
  ushort* agg   = (ushort*)alloc((size_t)N * 128 * 2);
  (void)ws_size; (void)n_in; (void)out_size;

  const int EB = (E + 255) / 256;
  const int GB = (N + 127) / 128;

  // CSR build
  hipMemsetAsync(cnt, 0, (size_t)N * 4, stream);
  hist_kernel<<<EB, 256, 0, stream>>>(dst, cnt, E);
  blocksum_kernel<<<NB, 256, 0, stream>>>(cnt, bsum, N);
  scanbsum_kernel<<<1, 256, 0, stream>>>(bsum, boff, NB, rowptr, N, E);
  writerowptr_kernel<<<NB, 256, 0, stream>>>(cnt, boff, rowptr, N);
  hipMemsetAsync(cnt, 0, (size_t)N * 4, stream);
  fill_kernel<<<EB, 256, 0, stream>>>(src, dst, rowptr, cnt, col, E);
  deginv_kernel<<<NB, 256, 0, stream>>>(rowptr, dinv, N);

  // weights -> bf16 transposed
  prep_weights<<<384, 256, 0, stream>>>(W_in, Wl, Wr, Bt_in, Bt_l);

  // input projection
  gemm_in<<<GB, 256, 0, stream>>>(x, Bt_in, b_in, bng_in, bnb_in, bnm_in, bnv_in, hA, N);

  // 3 SAGE layers: hA -> hB -> hA -> d_out(fp32)
  ushort* hbuf[2] = { hA, hB };
  for (int l = 0; l < 3; ++l) {
    const ushort* h_in = hbuf[l & 1];
    agg_kernel<<<(N + 3) / 4, 256, 0, stream>>>(rowptr, col, dinv, h_in, agg, N);
    const ushort* BtL = Bt_l + (size_t)l * 32768;
    const float* biasL = bl + l * 128;
    if (l < 2) {
      gemm_layer<false><<<GB, 256, 0, stream>>>(agg, h_in, BtL, biasL,
          bng + l * 128, bnb + l * 128, bnm + l * 128, bnv + l * 128,
          h_in, (void*)hbuf[(l + 1) & 1], N);
    } else {
      gemm_layer<true><<<GB, 256, 0, stream>>>(agg, h_in, BtL, biasL,
          bng + l * 128, bnb + l * 128, bnm + l * 128, bnv + l * 128,
          h_in, d_out, N);
    }
  }
}

// Round 3
// 503.376 us; speedup vs baseline: 1.7170x; 1.1994x over previous
//
#include <hip/hip_runtime.h>

#define BN_EPS 1e-5f

typedef __bf16 bf16x8 __attribute__((ext_vector_type(8)));
typedef float f32x4 __attribute__((ext_vector_type(4)));
typedef unsigned int uint;
typedef unsigned short ushort;

__device__ __forceinline__ ushort f2bf(float f) {
  union { float f; uint u; } v; v.f = f;
  uint r = v.u + 0x7FFF + ((v.u >> 16) & 1);   // RNE
  return (ushort)(r >> 16);
}
__device__ __forceinline__ float bf2f_lo(uint u) {
  union { uint i; float f; } v; v.i = u << 16; return v.f;
}
__device__ __forceinline__ float bf2f_hi(uint u) {
  union { uint i; float f; } v; v.i = u & 0xffff0000u; return v.f;
}
__device__ __forceinline__ uint pack2(float a, float b) {
  return (uint)f2bf(a) | ((uint)f2bf(b) << 16);
}

// ---------------- CSR build ----------------

__global__ void hist_kernel(const int* __restrict__ dst, int* __restrict__ cnt, int E) {
  int e = blockIdx.x * 256 + threadIdx.x;
  if (e < E) atomicAdd(&cnt[dst[e]], 1);
}

__device__ __forceinline__ int block_exscan256(int v, int tid, int* ws4) {
  __syncthreads();
  int lane = tid & 63, w = tid >> 6;
  int x = v;
  #pragma unroll
  for (int off = 1; off < 64; off <<= 1) {
    int y = __shfl_up(x, off, 64);
    if (lane >= off) x += y;
  }
  if (lane == 63) ws4[w] = x;
  __syncthreads();
  if (tid == 0) {
    int s = 0;
    for (int i = 0; i < 4; ++i) { int t = ws4[i]; ws4[i] = s; s += t; }
  }
  __syncthreads();
  return ws4[w] + x - v;
}

__global__ void blocksum_kernel(const int* __restrict__ cnt, int* __restrict__ bsum, int N) {
  __shared__ int ws4[4];
  int tid = threadIdx.x;
  int i = blockIdx.x * 256 + tid;
  int v = (i < N) ? cnt[i] : 0;
  #pragma unroll
  for (int off = 32; off > 0; off >>= 1) v += __shfl_down(v, off, 64);
  if ((tid & 63) == 0) ws4[tid >> 6] = v;
  __syncthreads();
  if (tid == 0) bsum[blockIdx.x] = ws4[0] + ws4[1] + ws4[2] + ws4[3];
}

__global__ void scanbsum_kernel(const int* __restrict__ bsum, int* __restrict__ boff,
                                int NB, int* __restrict__ rowptr, int N, int E) {
  __shared__ int ws4[4];
  __shared__ int tot;
  int tid = threadIdx.x;
  int carry = 0;
  for (int base = 0; base < NB; base += 256) {
    int i = base + tid;
    int v = (i < NB) ? bsum[i] : 0;
    int ex = block_exscan256(v, tid, ws4);
    if (i < NB) boff[i] = carry + ex;
    if (tid == 255) tot = ex + v;
    __syncthreads();
    carry += tot;
  }
  if (tid == 0) rowptr[N] = E;
}

__global__ void writerowptr_kernel(const int* __restrict__ cnt, const int* __restrict__ boff,
                                   int* __restrict__ rowptr, int N) {
  __shared__ int ws4[4];
  int tid = threadIdx.x;
  int i = blockIdx.x * 256 + tid;
  int v = (i < N) ? cnt[i] : 0;
  int ex = block_exscan256(v, tid, ws4);
  if (i < N) rowptr[i] = boff[blockIdx.x] + ex;
}

__global__ void fill_kernel(const int* __restrict__ src, const int* __restrict__ dst,
                            const int* __restrict__ rowptr, int* __restrict__ cur,
                            int* __restrict__ col, int E) {
  int e = blockIdx.x * 256 + threadIdx.x;
  if (e < E) {
    int d = dst[e];
    int p = rowptr[d] + atomicAdd(&cur[d], 1);
    col[p] = src[e];
  }
}

__global__ void deginv_kernel(const int* __restrict__ rowptr, float* __restrict__ dinv, int N) {
  int i = blockIdx.x * 256 + threadIdx.x;
  if (i < N) {
    int d = rowptr[i + 1] - rowptr[i];
    dinv[i] = 1.0f / (float)(d > 0 ? d : 1);
  }
}

// ---------------- weight prep: fragment-major bf16 ----------------
// Piece p in [0,16384): mat = p>>12 (0=input proj, 1..3=layers), rem = p&4095:
// nt = rem>>9 (0..7), kt = (rem>>6)&7, lane = rem&63 (quad=lane>>4, l16=lane&15).
// Piece holds Bt[n = nt*16+l16][k = kt*32+quad*8 + 0..7], Bt[n][k] = W[k][n].

__global__ void prep_weights_fm(const float* __restrict__ W_in, const float* __restrict__ Wl,
                                const float* __restrict__ Wr, ushort* __restrict__ Bfm) {
  int p = blockIdx.x * 256 + threadIdx.x;
  int mat = p >> 12, rem = p & 4095;
  int nt = rem >> 9, kt = (rem >> 6) & 7, lane = rem & 63;
  int n = nt * 16 + (lane & 15);
  int k0 = kt * 32 + (lane >> 4) * 8;
  ushort tmp[8];
  #pragma unroll
  for (int j = 0; j < 8; ++j) {
    int k = k0 + j;
    float v;
    if (mat == 0) v = W_in[k * 128 + n];
    else {
      int l = mat - 1;
      v = (k < 128) ? Wl[l * 16384 + k * 128 + n] : Wr[l * 16384 + (k - 128) * 128 + n];
    }
    tmp[j] = f2bf(v);
  }
  *(uint4*)&Bfm[(size_t)p * 8] = *(const uint4*)tmp;
}

// ---------------- mean aggregation (bf16 h): one wave per node, unroll 4 -------

__global__ void agg_kernel(const int* __restrict__ rowptr, const int* __restrict__ col,
                           const float* __restrict__ dinv, const ushort* __restrict__ h,
                           ushort* __restrict__ agg, int N) {
  int node = blockIdx.x * 4 + (threadIdx.x >> 6);
  if (node >= N) return;
  int lane = threadIdx.x & 63;
  int beg = rowptr[node], end = rowptr[node + 1];
  float ax = 0.f, ay = 0.f;
  int e = beg;
  for (; e + 3 < end; e += 4) {
    int s0 = col[e], s1 = col[e + 1], s2 = col[e + 2], s3 = col[e + 3];
    uint v0 = *(const uint*)(h + (size_t)s0 * 128 + lane * 2);
    uint v1 = *(const uint*)(h + (size_t)s1 * 128 + lane * 2);
    uint v2 = *(const uint*)(h + (size_t)s2 * 128 + lane * 2);
    uint v3 = *(const uint*)(h + (size_t)s3 * 128 + lane * 2);
    ax += (bf2f_lo(v0) + bf2f_lo(v1)) + (bf2f_lo(v2) + bf2f_lo(v3));
    ay += (bf2f_hi(v0) + bf2f_hi(v1)) + (bf2f_hi(v2) + bf2f_hi(v3));
  }
  for (; e < end; ++e) {
    uint v0 = *(const uint*)(h + (size_t)col[e] * 128 + lane * 2);
    ax += bf2f_lo(v0);
    ay += bf2f_hi(v0);
  }
  float di = dinv[node];
  *(uint*)(agg + (size_t)node * 128 + lane * 2) = pack2(ax * di, ay * di);
}

// ---------------- MFMA GEMM (layers): out = h_in + relu(bn([agg|h_in] @ W + bias)) ----
// BM=128, BN=128. 4 waves (2m x 2n), each 64x64. B staged once into LDS
// (fragment-major, conflict-free). A-frags stream global->VGPR, double-buffered,
// NO barriers in the K-loop. Epilogue bounces C through LDS for vector stores.

template<bool F32OUT>
__global__ __launch_bounds__(256, 2)
void gemm_layer(const ushort* __restrict__ A0, const ushort* __restrict__ A1,
                const ushort* __restrict__ Bfm, const float* __restrict__ bias,
                const float* __restrict__ gamma, const float* __restrict__ beta,
                const float* __restrict__ mean, const float* __restrict__ var,
                const ushort* __restrict__ residual, void* __restrict__ out, int N) {
  __shared__ ushort Bs[32768];
  int tid = threadIdx.x, wave = tid >> 6, lane = tid & 63;
  int wm = wave >> 1, wn = wave & 1, quad = lane >> 4, l16 = lane & 15;
  int m0 = blockIdx.x * 128;

  int rowm[4];
  #pragma unroll
  for (int mt = 0; mt < 4; ++mt) {
    int r = m0 + wm * 64 + mt * 16 + l16;
    rowm[mt] = r < N ? r : N - 1;
  }

  uint4 a_buf[2][4];
  {
    const ushort* bse = A0;
    int ko = quad * 8;
    #pragma unroll
    for (int mt = 0; mt < 4; ++mt)
      a_buf[0][mt] = *(const uint4*)(bse + (size_t)rowm[mt] * 128 + ko);
  }

  // stage B (coalesced, conflict-free)
  #pragma unroll
  for (int i = 0; i < 16; ++i) {
    int idx = i * 256 + tid;
    *(uint4*)&Bs[(size_t)idx * 8] = *(const uint4*)&Bfm[(size_t)idx * 8];
  }
  __syncthreads();

  f32x4 acc[4][4] = {};

  #pragma unroll
  for (int kt = 0; kt < 8; ++kt) {
    if (kt < 7) {
      const ushort* bse = (kt + 1 < 4) ? A0 : A1;
      int ko = ((kt + 1) & 3) * 32 + quad * 8;
      #pragma unroll
      for (int mt = 0; mt < 4; ++mt)
        a_buf[(kt + 1) & 1][mt] = *(const uint4*)(bse + (size_t)rowm[mt] * 128 + ko);
    }
    bf16x8 bfr[4];
    #pragma unroll
    for (int nt = 0; nt < 4; ++nt)
      bfr[nt] = *(bf16x8*)&Bs[((size_t)((wn * 4 + nt) * 8 + kt) * 64 + lane) * 8];
    #pragma unroll
    for (int mt = 0; mt < 4; ++mt) {
      bf16x8 af = __builtin_bit_cast(bf16x8, a_buf[kt & 1][mt]);
      #pragma unroll
      for (int nt = 0; nt < 4; ++nt)
        acc[mt][nt] = __builtin_amdgcn_mfma_f32_16x16x32_bf16(af, bfr[nt], acc[mt][nt], 0, 0, 0);
    }
  }

  // bias + BN + ReLU in registers
  #pragma unroll
  for (int nt = 0; nt < 4; ++nt) {
    int c = wn * 64 + nt * 16 + l16;
    float sc = gamma[c] * rsqrtf(var[c] + BN_EPS);
    float sh = beta[c] - mean[c] * sc;
    float bi = bias[c];
    #pragma unroll
    for (int mt = 0; mt < 4; ++mt)
      #pragma unroll
      for (int r = 0; r < 4; ++r)
        acc[mt][nt][r] = fmaxf((acc[mt][nt][r] + bi) * sc + sh, 0.f);
  }

  // bounce through LDS (reuse Bs) for vectorized residual+store
  __syncthreads();
  float* Cb = (float*)Bs + wave * (16 * 68);
  #pragma unroll
  for (int mt = 0; mt < 4; ++mt) {
    #pragma unroll
    for (int nt = 0; nt < 4; ++nt)
      #pragma unroll
      for (int r = 0; r < 4; ++r)
        Cb[(quad * 4 + r) * 68 + nt * 16 + l16] = acc[mt][nt][r];
    #pragma unroll
    for (int i = 0; i < 4; ++i) {
      int idx = i * 64 + lane, rowl = idx >> 4, seg = idx & 15;
      int grow = m0 + wm * 64 + mt * 16 + rowl;
      if (grow < N) {
        float4 vv = *(float4*)&Cb[rowl * 68 + seg * 4];
        uint2 rv = *(const uint2*)(residual + (size_t)grow * 128 + wn * 64 + seg * 4);
        vv.x += bf2f_lo(rv.x); vv.y += bf2f_hi(rv.x);
        vv.z += bf2f_lo(rv.y); vv.w += bf2f_hi(rv.y);
        if (F32OUT) {
          *(float4*)((float*)out + (size_t)grow * 128 + wn * 64 + seg * 4) = vv;
        } else {
          uint2 o;
          o.x = pack2(vv.x, vv.y); o.y = pack2(vv.z, vv.w);
          *(uint2*)((ushort*)out + (size_t)grow * 128 + wn * 64 + seg * 4) = o;
        }
      }
    }
  }
}

// ---------------- MFMA GEMM (input proj): h = relu(bn(x @ W_in + b)), x fp32 ------

__global__ __launch_bounds__(256, 2)
void gemm_in(const float* __restrict__ X, const ushort* __restrict__ Bfm,
             const float* __restrict__ bias,
             const float* __restrict__ gamma, const float* __restrict__ beta,
             const float* __restrict__ mean, const float* __restrict__ var,
             ushort* __restrict__ out, int N) {
  __shared__ ushort Bs[32768];
  int tid = threadIdx.x, wave = tid >> 6, lane = tid & 63;
  int wm = wave >> 1, wn = wave & 1, quad = lane >> 4, l16 = lane & 15;
  int m0 = blockIdx.x * 128;

  int rowm[4];
  #pragma unroll
  for (int mt = 0; mt < 4; ++mt) {
    int r = m0 + wm * 64 + mt * 16 + l16;
    rowm[mt] = r < N ? r : N - 1;
  }

  float4 f_buf[2][4][2];
  {
    int ko = quad * 8;
    #pragma unroll
    for (int mt = 0; mt < 4; ++mt) {
      const float* p = X + (size_t)rowm[mt] * 256 + ko;
      f_buf[0][mt][0] = *(const float4*)p;
      f_buf[0][mt][1] = *(const float4*)(p + 4);
    }
  }

  #pragma unroll
  for (int i = 0; i < 16; ++i) {
    int idx = i * 256 + tid;
    *(uint4*)&Bs[(size_t)idx * 8] = *(const uint4*)&Bfm[(size_t)idx * 8];
  }
  __syncthreads();

  f32x4 acc[4][4] = {};

  #pragma unroll
  for (int kt = 0; kt < 8; ++kt) {
    if (kt < 7) {
      int ko = (kt + 1) * 32 + quad * 8;
      #pragma unroll
      for (int mt = 0; mt < 4; ++mt) {
        const float* p = X + (size_t)rowm[mt] * 256 + ko;
        f_buf[(kt + 1) & 1][mt][0] = *(const float4*)p;
        f_buf[(kt + 1) & 1][mt][1] = *(const float4*)(p + 4);
      }
    }
    bf16x8 bfr[4];
    #pragma unroll
    for (int nt = 0; nt < 4; ++nt)
      bfr[nt] = *(bf16x8*)&Bs[((size_t)((wn * 4 + nt) * 8 + kt) * 64 + lane) * 8];
    #pragma unroll
    for (int mt = 0; mt < 4; ++mt) {
      float4 lo = f_buf[kt & 1][mt][0], hi = f_buf[kt & 1][mt][1];
      uint4 av;
      av.x = pack2(lo.x, lo.y); av.y = pack2(lo.z, lo.w);
      av.z = pack2(hi.x, hi.y); av.w = pack2(hi.z, hi.w);
      bf16x8 af = __builtin_bit_cast(bf16x8, av);
      #pragma unroll
      for (int nt = 0; nt < 4; ++nt)
        acc[mt][nt] = __builtin_amdgcn_mfma_f32_16x16x32_bf16(af, bfr[nt], acc[mt][nt], 0, 0, 0);
    }
  }

  #pragma unroll
  for (int nt = 0; nt < 4; ++nt) {
    int c = wn * 64 + nt * 16 + l16;
    float sc = gamma[c] * rsqrtf(var[c] + BN_EPS);
    float sh = beta[c] - mean[c] * sc;
    float bi = bias[c];
    #pragma unroll
    for (int mt = 0; mt < 4; ++mt)
      #pragma unroll
      for (int r = 0; r < 4; ++r)
        acc[mt][nt][r] = fmaxf((acc[mt][nt][r] + bi) * sc + sh, 0.f);
  }

  __syncthreads();
  float* Cb = (float*)Bs + wave * (16 * 68);
  #pragma unroll
  for (int mt = 0; mt < 4; ++mt) {
    #pragma unroll
    for (int nt = 0; nt < 4; ++nt)
      #pragma unroll
      for (int r = 0; r < 4; ++r)
        Cb[(quad * 4 + r) * 68 + nt * 16 + l16] = acc[mt][nt][r];
    #pragma unroll
    for (int i = 0; i < 4; ++i) {
      int idx = i * 64 + lane, rowl = idx >> 4, seg = idx & 15;
      int grow = m0 + wm * 64 + mt * 16 + rowl;
      if (grow < N) {
        float4 vv = *(float4*)&Cb[rowl * 68 + seg * 4];
        uint2 o;
        o.x = pack2(vv.x, vv.y); o.y = pack2(vv.z, vv.w);
        *(uint2*)(out + (size_t)grow * 128 + wn * 64 + seg * 4) = o;
      }
    }
  }
}

// ---------------- launch ----------------

extern "C" void kernel_launch(void* const* d_in, const int* in_sizes, int n_in,
                              void* d_out, int out_size, void* d_ws, size_t ws_size,
                              hipStream_t stream) {
  const float* x      = (const float*)d_in[0];
  const int*   eidx   = (const int*)d_in[1];
  const float* W_in   = (const float*)d_in[2];
  const float* b_in   = (const float*)d_in[3];
  const float* bng_in = (const float*)d_in[4];
  const float* bnb_in = (const float*)d_in[5];
  const float* bnm_in = (const float*)d_in[6];
  const float* bnv_in = (const float*)d_in[7];
  const float* Wl     = (const float*)d_in[8];
  const float* bl     = (const float*)d_in[9];
  const float* Wr     = (const float*)d_in[10];
  const float* bng    = (const float*)d_in[11];
  const float* bnb    = (const float*)d_in[12];
  const float* bnm    = (const float*)d_in[13];
  const float* bnv    = (const float*)d_in[14];

  const int N = in_sizes[0] / 256;
  const int E = in_sizes[1] / 2;
  const int NB = (N + 255) / 256;
  const int* src = eidx;
  const int* dst = eidx + E;

  char* ws = (char*)d_ws;
  size_t off = 0;
  auto alloc = [&](size_t bytes) {
    void* p = ws + off;
    off = (off + bytes + 255) & ~(size_t)255;
    return p;
  };
  int* cnt      = (int*)alloc((size_t)N * 4);
  int* rowptr   = (int*)alloc((size_t)(N + 1) * 4);
  int* bsum     = (int*)alloc((size_t)NB * 4);
  int* boff     = (int*)alloc((size_t)NB * 4);
  int* col      = (int*)alloc((size_t)E * 4);
  float* dinv   = (float*)alloc((size_t)N * 4);
  ushort* Bfm   = (ushort*)alloc(4 * 32768 * 2);   // frag-major: [in, l0, l1, l2]
  ushort* hA    = (ushort*)alloc((size_t)N * 128 * 2);
  ushort* hB    = (ushort*)alloc((size_t)N * 128 * 2);
  ushort* agg   = (ushort*)alloc((size_t)N * 128 * 2);
  (void)ws_size; (void)n_in; (void)out_size;

  const int EB = (E + 255) / 256;
  const int GB = (N + 127) / 128;

  // CSR build
  hipMemsetAsync(cnt, 0, (size_t)N * 4, stream);
  hist_kernel<<<EB, 256, 0, stream>>>(dst, cnt, E);
  blocksum_kernel<<<NB, 256, 0, stream>>>(cnt, bsum, N);
  scanbsum_kernel<<<1, 256, 0, stream>>>(bsum, boff, NB, rowptr, N, E);
  writerowptr_kernel<<<NB, 256, 0, stream>>>(cnt, boff, rowptr, N);
  hipMemsetAsync(cnt, 0, (size_t)N * 4, stream);
  fill_kernel<<<EB, 256, 0, stream>>>(src, dst, rowptr, cnt, col, E);
  deginv_kernel<<<NB, 256, 0, stream>>>(rowptr, dinv, N);

  // weights -> fragment-major bf16
  prep_weights_fm<<<64, 256, 0, stream>>>(W_in, Wl, Wr, Bfm);

  // input projection
  gemm_in<<<GB, 256, 0, stream>>>(x, Bfm, b_in, bng_in, bnb_in, bnm_in, bnv_in, hA, N);

  // 3 SAGE layers: hA -> hB -> hA -> d_out(fp32)
  ushort* hbuf[2] = { hA, hB };
  for (int l = 0; l < 3; ++l) {
    const ushort* h_in = hbuf[l & 1];
    agg_kernel<<<(N + 3) / 4, 256, 0, stream>>>(rowptr, col, dinv, h_in, agg, N);
    const ushort* BfmL = Bfm + (size_t)(l + 1) * 32768;
    const float* biasL = bl + l * 128;
    if (l < 2) {
      gemm_layer<false><<<GB, 256, 0, stream>>>(agg, h_in, BfmL, biasL,
          bng + l * 128, bnb + l * 128, bnm + l * 128, bnv + l * 128,
          h_in, (void*)hbuf[(l + 1) & 1], N);
    } else {
      gemm_layer<true><<<GB, 256, 0, stream>>>(agg, h_in, BfmL, biasL,
          bng + l * 128, bnb + l * 128, bnm + l * 128, bnv + l * 128,
          h_in, d_out, N);
    }
  }
}

// Round 4
// 490.789 us; speedup vs baseline: 1.7610x; 1.0256x over previous
//
#include <hip/hip_runtime.h>

#define BN_EPS 1e-5f

typedef __bf16 bf16x8 __attribute__((ext_vector_type(8)));
typedef float f32x4 __attribute__((ext_vector_type(4)));
typedef unsigned int uint;
typedef unsigned short ushort;

__device__ __forceinline__ ushort f2bf(float f) {
  union { float f; uint u; } v; v.f = f;
  uint r = v.u + 0x7FFF + ((v.u >> 16) & 1);   // RNE
  return (ushort)(r >> 16);
}
__device__ __forceinline__ float bf2f_lo(uint u) {
  union { uint i; float f; } v; v.i = u << 16; return v.f;
}
__device__ __forceinline__ float bf2f_hi(uint u) {
  union { uint i; float f; } v; v.i = u & 0xffff0000u; return v.f;
}
__device__ __forceinline__ uint pack2(float a, float b) {
  return (uint)f2bf(a) | ((uint)f2bf(b) << 16);
}

// barrier that waits only on LDS ops (lgkmcnt(0)), leaving global loads in flight.
// 0xC07F = vmcnt(63) expcnt(7) lgkmcnt(0) in gfx9 encoding.
__device__ __forceinline__ void lds_barrier() {
  asm volatile("" ::: "memory");
  __builtin_amdgcn_s_waitcnt(0xC07F);
  __builtin_amdgcn_s_barrier();
  asm volatile("" ::: "memory");
}

// ---------------- CSR build ----------------

__global__ void hist_kernel(const int* __restrict__ dst, int* __restrict__ cnt, int E) {
  int e = blockIdx.x * 256 + threadIdx.x;
  if (e < E) atomicAdd(&cnt[dst[e]], 1);
}

__device__ __forceinline__ int block_exscan256(int v, int tid, int* ws4) {
  __syncthreads();
  int lane = tid & 63, w = tid >> 6;
  int x = v;
  #pragma unroll
  for (int off = 1; off < 64; off <<= 1) {
    int y = __shfl_up(x, off, 64);
    if (lane >= off) x += y;
  }
  if (lane == 63) ws4[w] = x;
  __syncthreads();
  if (tid == 0) {
    int s = 0;
    for (int i = 0; i < 4; ++i) { int t = ws4[i]; ws4[i] = s; s += t; }
  }
  __syncthreads();
  return ws4[w] + x - v;
}

__global__ void blocksum_kernel(const int* __restrict__ cnt, int* __restrict__ bsum, int N) {
  __shared__ int ws4[4];
  int tid = threadIdx.x;
  int i = blockIdx.x * 256 + tid;
  int v = (i < N) ? cnt[i] : 0;
  #pragma unroll
  for (int off = 32; off > 0; off >>= 1) v += __shfl_down(v, off, 64);
  if ((tid & 63) == 0) ws4[tid >> 6] = v;
  __syncthreads();
  if (tid == 0) bsum[blockIdx.x] = ws4[0] + ws4[1] + ws4[2] + ws4[3];
}

__global__ void scanbsum_kernel(const int* __restrict__ bsum, int* __restrict__ boff,
                                int NB, int* __restrict__ rowptr, int N, int E) {
  __shared__ int ws4[4];
  __shared__ int tot;
  int tid = threadIdx.x;
  int carry = 0;
  for (int base = 0; base < NB; base += 256) {
    int i = base + tid;
    int v = (i < NB) ? bsum[i] : 0;
    int ex = block_exscan256(v, tid, ws4);
    if (i < NB) boff[i] = carry + ex;
    if (tid == 255) tot = ex + v;
    __syncthreads();
    carry += tot;
  }
  if (tid == 0) rowptr[N] = E;
}

__global__ void writerowptr_kernel(const int* __restrict__ cnt, const int* __restrict__ boff,
                                   int* __restrict__ rowptr, int N) {
  __shared__ int ws4[4];
  int tid = threadIdx.x;
  int i = blockIdx.x * 256 + tid;
  int v = (i < N) ? cnt[i] : 0;
  int ex = block_exscan256(v, tid, ws4);
  if (i < N) rowptr[i] = boff[blockIdx.x] + ex;
}

__global__ void fill_kernel(const int* __restrict__ src, const int* __restrict__ dst,
                            const int* __restrict__ rowptr, int* __restrict__ cur,
                            int* __restrict__ col, int E) {
  int e = blockIdx.x * 256 + threadIdx.x;
  if (e < E) {
    int d = dst[e];
    int p = rowptr[d] + atomicAdd(&cur[d], 1);
    col[p] = src[e];
  }
}

__global__ void deginv_kernel(const int* __restrict__ rowptr, float* __restrict__ dinv, int N) {
  int i = blockIdx.x * 256 + threadIdx.x;
  if (i < N) {
    int d = rowptr[i + 1] - rowptr[i];
    dinv[i] = 1.0f / (float)(d > 0 ? d : 1);
  }
}

// ---------------- weight prep: split-K fragment-major bf16 ----------------
// Piece p in [0,16384): mat = p>>12, rem = p&4095, half = rem>>11, rem2 = rem&2047,
// nt = rem2>>8, kt2 = (rem2>>6)&3, lane = rem2&63.
// Piece holds Bt[n = nt*16+(lane&15)][k = (half*4+kt2)*32+(lane>>4)*8 + 0..7],
// Bt[n][k] = W[k][n]. Each (mat,half) slab is a contiguous 32 KB.

__global__ void prep_weights_fm(const float* __restrict__ W_in, const float* __restrict__ Wl,
                                const float* __restrict__ Wr, ushort* __restrict__ Bfm) {
  int p = blockIdx.x * 256 + threadIdx.x;
  int mat = p >> 12;
  int rem = p & 4095;
  int half = rem >> 11;
  int rem2 = rem & 2047;
  int nt = rem2 >> 8, kt2 = (rem2 >> 6) & 3, lane = rem2 & 63;
  int n = nt * 16 + (lane & 15);
  int k0 = (half * 4 + kt2) * 32 + (lane >> 4) * 8;
  ushort tmp[8];
  #pragma unroll
  for (int j = 0; j < 8; ++j) {
    int k = k0 + j;
    float v;
    if (mat == 0) v = W_in[k * 128 + n];
    else {
      int l = mat - 1;
      v = (k < 128) ? Wl[l * 16384 + k * 128 + n] : Wr[l * 16384 + (k - 128) * 128 + n];
    }
    tmp[j] = f2bf(v);
  }
  *(uint4*)&Bfm[(size_t)p * 8] = *(const uint4*)tmp;
}

// ---------------- mean aggregation: 2 nodes per wave (32 lanes each) ----------

__global__ void agg_kernel(const int* __restrict__ rowptr, const int* __restrict__ col,
                           const float* __restrict__ dinv, const ushort* __restrict__ h,
                           ushort* __restrict__ agg, int N) {
  int node = blockIdx.x * 8 + (threadIdx.x >> 5);
  if (node >= N) return;
  int lane = threadIdx.x & 31;
  const ushort* hp = h + lane * 4;
  int beg = rowptr[node], end = rowptr[node + 1];
  float a0 = 0.f, a1 = 0.f, a2 = 0.f, a3 = 0.f;
  int e = beg;
  for (; e + 3 < end; e += 4) {
    uint2 v0 = *(const uint2*)(hp + (size_t)col[e] * 128);
    uint2 v1 = *(const uint2*)(hp + (size_t)col[e + 1] * 128);
    uint2 v2 = *(const uint2*)(hp + (size_t)col[e + 2] * 128);
    uint2 v3 = *(const uint2*)(hp + (size_t)col[e + 3] * 128);
    a0 += (bf2f_lo(v0.x) + bf2f_lo(v1.x)) + (bf2f_lo(v2.x) + bf2f_lo(v3.x));
    a1 += (bf2f_hi(v0.x) + bf2f_hi(v1.x)) + (bf2f_hi(v2.x) + bf2f_hi(v3.x));
    a2 += (bf2f_lo(v0.y) + bf2f_lo(v1.y)) + (bf2f_lo(v2.y) + bf2f_lo(v3.y));
    a3 += (bf2f_hi(v0.y) + bf2f_hi(v1.y)) + (bf2f_hi(v2.y) + bf2f_hi(v3.y));
  }
  for (; e < end; ++e) {
    uint2 v0 = *(const uint2*)(hp + (size_t)col[e] * 128);
    a0 += bf2f_lo(v0.x); a1 += bf2f_hi(v0.x);
    a2 += bf2f_lo(v0.y); a3 += bf2f_hi(v0.y);
  }
  float di = dinv[node];
  uint2 o;
  o.x = pack2(a0 * di, a1 * di);
  o.y = pack2(a2 * di, a3 * di);
  *(uint2*)(agg + (size_t)node * 128 + lane * 4) = o;
}

// ---------------- MFMA GEMM (layers) ----------------
// BM=128, BN=128, 4 waves (2m x 2n), 64x64/wave. B staged in two 32 KB halves
// (lgkm-only barriers). A-frags stream global->VGPR double-buffered; the kt=4
// prefetch stays in flight across the B-half swap.

template<bool F32OUT>
__global__ __launch_bounds__(256, 3)
void gemm_layer(const ushort* __restrict__ A0, const ushort* __restrict__ A1,
                const ushort* __restrict__ Bfm, const float* __restrict__ bias,
                const float* __restrict__ gamma, const float* __restrict__ beta,
                const float* __restrict__ mean, const float* __restrict__ var,
                const ushort* __restrict__ residual, void* __restrict__ out, int N) {
  __shared__ ushort Bs[16384];   // 32 KB: one K-half, fragment-major
  int tid = threadIdx.x, wave = tid >> 6, lane = tid & 63;
  int wm = wave >> 1, wn = wave & 1, quad = lane >> 4, l16 = lane & 15;
  int m0 = blockIdx.x * 128;

  int rowm[4];
  #pragma unroll
  for (int mt = 0; mt < 4; ++mt) {
    int r = m0 + wm * 64 + mt * 16 + l16;
    rowm[mt] = r < N ? r : N - 1;
  }

  uint4 a_buf[2][4];
  #pragma unroll
  for (int mt = 0; mt < 4; ++mt)
    a_buf[0][mt] = *(const uint4*)(A0 + (size_t)rowm[mt] * 128 + quad * 8);

  // stage B half 0
  #pragma unroll
  for (int i = 0; i < 8; ++i) {
    int idx = i * 256 + tid;
    *(uint4*)&Bs[idx * 8] = *(const uint4*)&Bfm[idx * 8];
  }
  lds_barrier();

  f32x4 acc[4][4] = {};

  #pragma unroll
  for (int h = 0; h < 2; ++h) {
    #pragma unroll
    for (int k2 = 0; k2 < 4; ++k2) {
      int kt = h * 4 + k2;
      if (kt < 7) {
        const ushort* bse = (kt + 1 < 4) ? A0 : A1;
        int ko = ((kt + 1) & 3) * 32 + quad * 8;
        #pragma unroll
        for (int mt = 0; mt < 4; ++mt)
          a_buf[(kt + 1) & 1][mt] = *(const uint4*)(bse + (size_t)rowm[mt] * 128 + ko);
      }
      bf16x8 bfr[4];
      #pragma unroll
      for (int nt = 0; nt < 4; ++nt)
        bfr[nt] = *(bf16x8*)&Bs[(((wn * 4 + nt) * 4 + k2) * 64 + lane) * 8];
      #pragma unroll
      for (int mt = 0; mt < 4; ++mt) {
        bf16x8 af = __builtin_bit_cast(bf16x8, a_buf[kt & 1][mt]);
        #pragma unroll
        for (int nt = 0; nt < 4; ++nt)
          acc[mt][nt] = __builtin_amdgcn_mfma_f32_16x16x32_bf16(af, bfr[nt], acc[mt][nt], 0, 0, 0);
      }
    }
    if (h == 0) {
      lds_barrier();   // all waves done reading half 0
      #pragma unroll
      for (int i = 0; i < 8; ++i) {
        int idx = i * 256 + tid;
        *(uint4*)&Bs[idx * 8] = *(const uint4*)&Bfm[16384 + idx * 8];
      }
      lds_barrier();
    }
  }

  // bias + BN + ReLU in registers
  #pragma unroll
  for (int nt = 0; nt < 4; ++nt) {
    int c = wn * 64 + nt * 16 + l16;
    float sc = gamma[c] * rsqrtf(var[c] + BN_EPS);
    float sh = beta[c] - mean[c] * sc;
    float bi = bias[c];
    #pragma unroll
    for (int mt = 0; mt < 4; ++mt)
      #pragma unroll
      for (int r = 0; r < 4; ++r)
        acc[mt][nt][r] = fmaxf((acc[mt][nt][r] + bi) * sc + sh, 0.f);
  }

  // bounce through LDS (reuse Bs) for vectorized residual+store
  lds_barrier();
  float* Cb = (float*)Bs + wave * (16 * 68);
  #pragma unroll
  for (int mt = 0; mt < 4; ++mt) {
    #pragma unroll
    for (int nt = 0; nt < 4; ++nt)
      #pragma unroll
      for (int r = 0; r < 4; ++r)
        Cb[(quad * 4 + r) * 68 + nt * 16 + l16] = acc[mt][nt][r];
    #pragma unroll
    for (int i = 0; i < 4; ++i) {
      int idx = i * 64 + lane, rowl = idx >> 4, seg = idx & 15;
      int grow = m0 + wm * 64 + mt * 16 + rowl;
      if (grow < N) {
        float4 vv = *(float4*)&Cb[rowl * 68 + seg * 4];
        uint2 rv = *(const uint2*)(residual + (size_t)grow * 128 + wn * 64 + seg * 4);
        vv.x += bf2f_lo(rv.x); vv.y += bf2f_hi(rv.x);
        vv.z += bf2f_lo(rv.y); vv.w += bf2f_hi(rv.y);
        if (F32OUT) {
          *(float4*)((float*)out + (size_t)grow * 128 + wn * 64 + seg * 4) = vv;
        } else {
          uint2 o;
          o.x = pack2(vv.x, vv.y); o.y = pack2(vv.z, vv.w);
          *(uint2*)((ushort*)out + (size_t)grow * 128 + wn * 64 + seg * 4) = o;
        }
      }
    }
  }
}

// ---------------- MFMA GEMM (input proj): h = relu(bn(x @ W_in + b)), x fp32 ------

__global__ __launch_bounds__(256, 3)
void gemm_in(const float* __restrict__ X, const ushort* __restrict__ Bfm,
             const float* __restrict__ bias,
             const float* __restrict__ gamma, const float* __restrict__ beta,
             const float* __restrict__ mean, const float* __restrict__ var,
             ushort* __restrict__ out, int N) {
  __shared__ ushort Bs[16384];
  int tid = threadIdx.x, wave = tid >> 6, lane = tid & 63;
  int wm = wave >> 1, wn = wave & 1, quad = lane >> 4, l16 = lane & 15;
  int m0 = blockIdx.x * 128;

  int rowm[4];
  #pragma unroll
  for (int mt = 0; mt < 4; ++mt) {
    int r = m0 + wm * 64 + mt * 16 + l16;
    rowm[mt] = r < N ? r : N - 1;
  }

  float4 f_buf[2][4][2];
  #pragma unroll
  for (int mt = 0; mt < 4; ++mt) {
    const float* p = X + (size_t)rowm[mt] * 256 + quad * 8;
    f_buf[0][mt][0] = *(const float4*)p;
    f_buf[0][mt][1] = *(const float4*)(p + 4);
  }

  #pragma unroll
  for (int i = 0; i < 8; ++i) {
    int idx = i * 256 + tid;
    *(uint4*)&Bs[idx * 8] = *(const uint4*)&Bfm[idx * 8];
  }
  lds_barrier();

  f32x4 acc[4][4] = {};

  #pragma unroll
  for (int h = 0; h < 2; ++h) {
    #pragma unroll
    for (int k2 = 0; k2 < 4; ++k2) {
      int kt = h * 4 + k2;
      if (kt < 7) {
        int ko = (kt + 1) * 32 + quad * 8;
        #pragma unroll
        for (int mt = 0; mt < 4; ++mt) {
          const float* p = X + (size_t)rowm[mt] * 256 + ko;
          f_buf[(kt + 1) & 1][mt][0] = *(const float4*)p;
          f_buf[(kt + 1) & 1][mt][1] = *(const float4*)(p + 4);
        }
      }
      bf16x8 bfr[4];
      #pragma unroll
      for (int nt = 0; nt < 4; ++nt)
        bfr[nt] = *(bf16x8*)&Bs[(((wn * 4 + nt) * 4 + k2) * 64 + lane) * 8];
      #pragma unroll
      for (int mt = 0; mt < 4; ++mt) {
        float4 lo = f_buf[kt & 1][mt][0], hi = f_buf[kt & 1][mt][1];
        uint4 av;
        av.x = pack2(lo.x, lo.y); av.y = pack2(lo.z, lo.w);
        av.z = pack2(hi.x, hi.y); av.w = pack2(hi.z, hi.w);
        bf16x8 af = __builtin_bit_cast(bf16x8, av);
        #pragma unroll
        for (int nt = 0; nt < 4; ++nt)
          acc[mt][nt] = __builtin_amdgcn_mfma_f32_16x16x32_bf16(af, bfr[nt], acc[mt][nt], 0, 0, 0);
      }
    }
    if (h == 0) {
      lds_barrier();
      #pragma unroll
      for (int i = 0; i < 8; ++i) {
        int idx = i * 256 + tid;
        *(uint4*)&Bs[idx * 8] = *(const uint4*)&Bfm[16384 + idx * 8];
      }
      lds_barrier();
    }
  }

  #pragma unroll
  for (int nt = 0; nt < 4; ++nt) {
    int c = wn * 64 + nt * 16 + l16;
    float sc = gamma[c] * rsqrtf(var[c] + BN_EPS);
    float sh = beta[c] - mean[c] * sc;
    float bi = bias[c];
    #pragma unroll
    for (int mt = 0; mt < 4; ++mt)
      #pragma unroll
      for (int r = 0; r < 4; ++r)
        acc[mt][nt][r] = fmaxf((acc[mt][nt][r] + bi) * sc + sh, 0.f);
  }

  lds_barrier();
  float* Cb = (float*)Bs + wave * (16 * 68);
  #pragma unroll
  for (int mt = 0; mt < 4; ++mt) {
    #pragma unroll
    for (int nt = 0; nt < 4; ++nt)
      #pragma unroll
      for (int r = 0; r < 4; ++r)
        Cb[(quad * 4 + r) * 68 + nt * 16 + l16] = acc[mt][nt][r];
    #pragma unroll
    for (int i = 0; i < 4; ++i) {
      int idx = i * 64 + lane, rowl = idx >> 4, seg = idx & 15;
      int grow = m0 + wm * 64 + mt * 16 + rowl;
      if (grow < N) {
        float4 vv = *(float4*)&Cb[rowl * 68 + seg * 4];
        uint2 o;
        o.x = pack2(vv.x, vv.y); o.y = pack2(vv.z, vv.w);
        *(uint2*)(out + (size_t)grow * 128 + wn * 64 + seg * 4) = o;
      }
    }
  }
}

// ---------------- launch ----------------

extern "C" void kernel_launch(void* const* d_in, const int* in_sizes, int n_in,
                              void* d_out, int out_size, void* d_ws, size_t ws_size,
                              hipStream_t stream) {
  const float* x      = (const float*)d_in[0];
  const int*   eidx   = (const int*)d_in[1];
  const float* W_in   = (const float*)d_in[2];
  const float* b_in   = (const float*)d_in[3];
  const float* bng_in = (const float*)d_in[4];
  const float* bnb_in = (const float*)d_in[5];
  const float* bnm_in = (const float*)d_in[6];
  const float* bnv_in = (const float*)d_in[7];
  const float* Wl     = (const float*)d_in[8];
  const float* bl     = (const float*)d_in[9];
  const float* Wr     = (const float*)d_in[10];
  const float* bng    = (const float*)d_in[11];
  const float* bnb    = (const float*)d_in[12];
  const float* bnm    = (const float*)d_in[13];
  const float* bnv    = (const float*)d_in[14];

  const int N = in_sizes[0] / 256;
  const int E = in_sizes[1] / 2;
  const int NB = (N + 255) / 256;
  const int* src = eidx;
  const int* dst = eidx + E;

  char* ws = (char*)d_ws;
  size_t off = 0;
  auto alloc = [&](size_t bytes) {
    void* p = ws + off;
    off = (off + bytes + 255) & ~(size_t)255;
    return p;
  };
  int* cnt      = (int*)alloc((size_t)N * 4);
  int* rowptr   = (int*)alloc((size_t)(N + 1) * 4);
  int* bsum     = (int*)alloc((size_t)NB * 4);
  int* boff     = (int*)alloc((size_t)NB * 4);
  int* col      = (int*)alloc((size_t)E * 4);
  float* dinv   = (float*)alloc((size_t)N * 4);
  ushort* Bfm   = (ushort*)alloc(4 * 32768 * 2);   // split-K frag-major: [in, l0, l1, l2]
  ushort* hA    = (ushort*)alloc((size_t)N * 128 * 2);
  ushort* hB    = (ushort*)alloc((size_t)N * 128 * 2);
  ushort* agg   = (ushort*)alloc((size_t)N * 128 * 2);
  (void)ws_size; (void)n_in; (void)out_size;

  const int EB = (E + 255) / 256;
  const int GB = (N + 127) / 128;

  // CSR build
  hipMemsetAsync(cnt, 0, (size_t)N * 4, stream);
  hist_kernel<<<EB, 256, 0, stream>>>(dst, cnt, E);
  blocksum_kernel<<<NB, 256, 0, stream>>>(cnt, bsum, N);
  scanbsum_kernel<<<1, 256, 0, stream>>>(bsum, boff, NB, rowptr, N, E);
  writerowptr_kernel<<<NB, 256, 0, stream>>>(cnt, boff, rowptr, N);
  hipMemsetAsync(cnt, 0, (size_t)N * 4, stream);
  fill_kernel<<<EB, 256, 0, stream>>>(src, dst, rowptr, cnt, col, E);
  deginv_kernel<<<NB, 256, 0, stream>>>(rowptr, dinv, N);

  // weights -> split-K fragment-major bf16
  prep_weights_fm<<<64, 256, 0, stream>>>(W_in, Wl, Wr, Bfm);

  // input projection
  gemm_in<<<GB, 256, 0, stream>>>(x, Bfm, b_in, bng_in, bnb_in, bnm_in, bnv_in, hA, N);

  // 3 SAGE layers: hA -> hB -> hA -> d_out(fp32)
  ushort* hbuf[2] = { hA, hB };
  for (int l = 0; l < 3; ++l) {
    const ushort* h_in = hbuf[l & 1];
    agg_kernel<<<(N + 7) / 8, 256, 0, stream>>>(rowptr, col, dinv, h_in, agg, N);
    const ushort* BfmL = Bfm + (size_t)(l + 1) * 32768;
    const float* biasL = bl + l * 128;
    if (l < 2) {
      gemm_layer<false><<<GB, 256, 0, stream>>>(agg, h_in, BfmL, biasL,
          bng + l * 128, bnb + l * 128, bnm + l * 128, bnv + l * 128,
          h_in, (void*)hbuf[(l + 1) & 1], N);
    } else {
      gemm_layer<true><<<GB, 256, 0, stream>>>(agg, h_in, BfmL, biasL,
          bng + l * 128, bnb + l * 128, bnm + l * 128, bnv + l * 128,
          h_in, d_out, N);
    }
  }
}

// Round 5
// 479.087 us; speedup vs baseline: 1.8040x; 1.0244x over previous
//
#include <hip/hip_runtime.h>

#define BN_EPS 1e-5f

typedef __bf16 bf16x8 __attribute__((ext_vector_type(8)));
typedef float f32x4 __attribute__((ext_vector_type(4)));
typedef unsigned int uint;
typedef unsigned short ushort;

__device__ __forceinline__ ushort f2bf(float f) {
  union { float f; uint u; } v; v.f = f;
  uint r = v.u + 0x7FFF + ((v.u >> 16) & 1);   // RNE
  return (ushort)(r >> 16);
}
__device__ __forceinline__ float bf2f_lo(uint u) {
  union { uint i; float f; } v; v.i = u << 16; return v.f;
}
__device__ __forceinline__ float bf2f_hi(uint u) {
  union { uint i; float f; } v; v.i = u & 0xffff0000u; return v.f;
}
__device__ __forceinline__ uint pack2(float a, float b) {
  return (uint)f2bf(a) | ((uint)f2bf(b) << 16);
}

// ---------------- CSR build ----------------

__global__ void hist_kernel(const int* __restrict__ dst, int* __restrict__ cnt, int E) {
  int e = blockIdx.x * 256 + threadIdx.x;
  if (e < E) atomicAdd(&cnt[dst[e]], 1);
}

__device__ __forceinline__ int block_exscan256(int v, int tid, int* ws4) {
  __syncthreads();
  int lane = tid & 63, w = tid >> 6;
  int x = v;
  #pragma unroll
  for (int off = 1; off < 64; off <<= 1) {
    int y = __shfl_up(x, off, 64);
    if (lane >= off) x += y;
  }
  if (lane == 63) ws4[w] = x;
  __syncthreads();
  if (tid == 0) {
    int s = 0;
    for (int i = 0; i < 4; ++i) { int t = ws4[i]; ws4[i] = s; s += t; }
  }
  __syncthreads();
  return ws4[w] + x - v;
}

__global__ void blocksum_kernel(const int* __restrict__ cnt, int* __restrict__ bsum, int N) {
  __shared__ int ws4[4];
  int tid = threadIdx.x;
  int i = blockIdx.x * 256 + tid;
  int v = (i < N) ? cnt[i] : 0;
  #pragma unroll
  for (int off = 32; off > 0; off >>= 1) v += __shfl_down(v, off, 64);
  if ((tid & 63) == 0) ws4[tid >> 6] = v;
  __syncthreads();
  if (tid == 0) bsum[blockIdx.x] = ws4[0] + ws4[1] + ws4[2] + ws4[3];
}

__global__ void scanbsum_kernel(const int* __restrict__ bsum, int* __restrict__ boff,
                                int NB, int* __restrict__ rowptr, int N, int E) {
  __shared__ int ws4[4];
  __shared__ int tot;
  int tid = threadIdx.x;
  int carry = 0;
  for (int base = 0; base < NB; base += 256) {
    int i = base + tid;
    int v = (i < NB) ? bsum[i] : 0;
    int ex = block_exscan256(v, tid, ws4);
    if (i < NB) boff[i] = carry + ex;
    if (tid == 255) tot = ex + v;
    __syncthreads();
    carry += tot;
  }
  if (tid == 0) rowptr[N] = E;
}

__global__ void writerowptr_kernel(const int* __restrict__ cnt, const int* __restrict__ boff,
                                   int* __restrict__ rowptr, int N) {
  __shared__ int ws4[4];
  int tid = threadIdx.x;
  int i = blockIdx.x * 256 + tid;
  int v = (i < N) ? cnt[i] : 0;
  int ex = block_exscan256(v, tid, ws4);
  if (i < N) rowptr[i] = boff[blockIdx.x] + ex;
}

__global__ void fill_kernel(const int* __restrict__ src, const int* __restrict__ dst,
                            const int* __restrict__ rowptr, int* __restrict__ cur,
                            int* __restrict__ col, int E) {
  int e = blockIdx.x * 256 + threadIdx.x;
  if (e < E) {
    int d = dst[e];
    int p = rowptr[d] + atomicAdd(&cur[d], 1);
    col[p] = src[e];
  }
}

// ---------------- weight prep: split-K fragment-major bf16 ----------------
// Piece p: mat = p>>12, rem = p&4095, half = rem>>11, rem2 = rem&2047,
// nt = rem2>>8, kt2 = (rem2>>6)&3, lane = rem2&63.
// Piece = Bt[n = nt*16+(lane&15)][k = (half*4+kt2)*32+(lane>>4)*8 + 0..7].

__global__ void prep_weights_fm(const float* __restrict__ W_in, const float* __restrict__ Wl,
                                const float* __restrict__ Wr, ushort* __restrict__ Bfm) {
  int p = blockIdx.x * 256 + threadIdx.x;
  int mat = p >> 12;
  int rem = p & 4095;
  int half = rem >> 11;
  int rem2 = rem & 2047;
  int nt = rem2 >> 8, kt2 = (rem2 >> 6) & 3, lane = rem2 & 63;
  int n = nt * 16 + (lane & 15);
  int k0 = (half * 4 + kt2) * 32 + (lane >> 4) * 8;
  ushort tmp[8];
  #pragma unroll
  for (int j = 0; j < 8; ++j) {
    int k = k0 + j;
    float v;
    if (mat == 0) v = W_in[k * 128 + n];
    else {
      int l = mat - 1;
      v = (k < 128) ? Wl[l * 16384 + k * 128 + n] : Wr[l * 16384 + (k - 128) * 128 + n];
    }
    tmp[j] = f2bf(v);
  }
  *(uint4*)&Bfm[(size_t)p * 8] = *(const uint4*)tmp;
}

// ---------------- mean aggregation: 2 nodes per wave, deg inline ----------

__global__ void agg_kernel(const int* __restrict__ rowptr, const int* __restrict__ col,
                           const ushort* __restrict__ h, ushort* __restrict__ agg, int N) {
  int node = blockIdx.x * 8 + (threadIdx.x >> 5);
  if (node >= N) return;
  int lane = threadIdx.x & 31;
  const ushort* hp = h + lane * 4;
  int beg = rowptr[node], end = rowptr[node + 1];
  int deg = end - beg;
  float di = 1.0f / (float)(deg > 0 ? deg : 1);
  float a0 = 0.f, a1 = 0.f, a2 = 0.f, a3 = 0.f;
  int e = beg;
  for (; e + 3 < end; e += 4) {
    uint2 v0 = *(const uint2*)(hp + (size_t)col[e] * 128);
    uint2 v1 = *(const uint2*)(hp + (size_t)col[e + 1] * 128);
    uint2 v2 = *(const uint2*)(hp + (size_t)col[e + 2] * 128);
    uint2 v3 = *(const uint2*)(hp + (size_t)col[e + 3] * 128);
    a0 += (bf2f_lo(v0.x) + bf2f_lo(v1.x)) + (bf2f_lo(v2.x) + bf2f_lo(v3.x));
    a1 += (bf2f_hi(v0.x) + bf2f_hi(v1.x)) + (bf2f_hi(v2.x) + bf2f_hi(v3.x));
    a2 += (bf2f_lo(v0.y) + bf2f_lo(v1.y)) + (bf2f_lo(v2.y) + bf2f_lo(v3.y));
    a3 += (bf2f_hi(v0.y) + bf2f_hi(v1.y)) + (bf2f_hi(v2.y) + bf2f_hi(v3.y));
  }
  for (; e < end; ++e) {
    uint2 v0 = *(const uint2*)(hp + (size_t)col[e] * 128);
    a0 += bf2f_lo(v0.x); a1 += bf2f_hi(v0.x);
    a2 += bf2f_lo(v0.y); a3 += bf2f_hi(v0.y);
  }
  uint2 o;
  o.x = pack2(a0 * di, a1 * di);
  o.y = pack2(a2 * di, a3 * di);
  *(uint2*)(agg + (size_t)node * 128 + lane * 4) = o;
}

// ---------------- MFMA GEMM (layers): no LDS in K-loop, no barriers -----------
// BM=128, BN=128, 4 waves (2m x 2n), 64x64/wave. B-frags load straight from
// global Bfm (L2-hot, coalesced); A + B double-buffered in VGPRs with a
// sched_barrier pinning the prefetch ahead of the MFMAs.

template<bool F32OUT>
__global__ __launch_bounds__(256, 3)
void gemm_layer(const ushort* __restrict__ A0, const ushort* __restrict__ A1,
                const ushort* __restrict__ Bfm, const float* __restrict__ bias,
                const float* __restrict__ gamma, const float* __restrict__ beta,
                const float* __restrict__ mean, const float* __restrict__ var,
                const ushort* __restrict__ residual, void* __restrict__ out, int N) {
  __shared__ float Cb_all[4 * 16 * 68];   // per-wave private epilogue bounce
  int tid = threadIdx.x, wave = tid >> 6, lane = tid & 63;
  int wm = wave >> 1, wn = wave & 1, quad = lane >> 4, l16 = lane & 15;
  int m0 = blockIdx.x * 128;

  int rowm[4];
  #pragma unroll
  for (int mt = 0; mt < 4; ++mt) {
    int r = m0 + wm * 64 + mt * 16 + l16;
    rowm[mt] = r < N ? r : N - 1;
  }

  uint4 a_buf[2][4], b_buf[2][4];
  // preload kt=0
  #pragma unroll
  for (int mt = 0; mt < 4; ++mt)
    a_buf[0][mt] = *(const uint4*)(A0 + (size_t)rowm[mt] * 128 + quad * 8);
  {
    const ushort* bp = Bfm + (size_t)(wn * 4 * 256 + lane) * 8;
    #pragma unroll
    for (int nt = 0; nt < 4; ++nt)
      b_buf[0][nt] = *(const uint4*)(bp + nt * 2048);
  }

  f32x4 acc[4][4] = {};

  #pragma unroll
  for (int kt = 0; kt < 8; ++kt) {
    if (kt < 7) {
      int k1 = kt + 1;
      const ushort* bse = (k1 < 4) ? A0 : A1;
      int ko = (k1 & 3) * 32 + quad * 8;
      #pragma unroll
      for (int mt = 0; mt < 4; ++mt)
        a_buf[k1 & 1][mt] = *(const uint4*)(bse + (size_t)rowm[mt] * 128 + ko);
      const ushort* bp = Bfm + ((size_t)(k1 >> 2) * 16384 +
                                (size_t)((wn * 4) * 256 + (k1 & 3) * 64 + lane) * 8);
      #pragma unroll
      for (int nt = 0; nt < 4; ++nt)
        b_buf[k1 & 1][nt] = *(const uint4*)(bp + nt * 2048);
    }
    __builtin_amdgcn_sched_barrier(0);   // keep the prefetch issued before MFMAs
    #pragma unroll
    for (int mt = 0; mt < 4; ++mt) {
      bf16x8 af = __builtin_bit_cast(bf16x8, a_buf[kt & 1][mt]);
      #pragma unroll
      for (int nt = 0; nt < 4; ++nt)
        acc[mt][nt] = __builtin_amdgcn_mfma_f32_16x16x32_bf16(
            af, __builtin_bit_cast(bf16x8, b_buf[kt & 1][nt]), acc[mt][nt], 0, 0, 0);
    }
  }

  // bias + BN + ReLU in registers
  #pragma unroll
  for (int nt = 0; nt < 4; ++nt) {
    int c = wn * 64 + nt * 16 + l16;
    float sc = gamma[c] * rsqrtf(var[c] + BN_EPS);
    float sh = beta[c] - mean[c] * sc;
    float bi = bias[c];
    #pragma unroll
    for (int mt = 0; mt < 4; ++mt)
      #pragma unroll
      for (int r = 0; r < 4; ++r)
        acc[mt][nt][r] = fmaxf((acc[mt][nt][r] + bi) * sc + sh, 0.f);
  }

  // per-wave LDS bounce for vectorized residual+store (no barriers needed)
  float* Cb = Cb_all + wave * (16 * 68);
  #pragma unroll
  for (int mt = 0; mt < 4; ++mt) {
    #pragma unroll
    for (int nt = 0; nt < 4; ++nt)
      #pragma unroll
      for (int r = 0; r < 4; ++r)
        Cb[(quad * 4 + r) * 68 + nt * 16 + l16] = acc[mt][nt][r];
    #pragma unroll
    for (int i = 0; i < 4; ++i) {
      int idx = i * 64 + lane, rowl = idx >> 4, seg = idx & 15;
      int grow = m0 + wm * 64 + mt * 16 + rowl;
      if (grow < N) {
        float4 vv = *(float4*)&Cb[rowl * 68 + seg * 4];
        uint2 rv = *(const uint2*)(residual + (size_t)grow * 128 + wn * 64 + seg * 4);
        vv.x += bf2f_lo(rv.x); vv.y += bf2f_hi(rv.x);
        vv.z += bf2f_lo(rv.y); vv.w += bf2f_hi(rv.y);
        if (F32OUT) {
          *(float4*)((float*)out + (size_t)grow * 128 + wn * 64 + seg * 4) = vv;
        } else {
          uint2 o;
          o.x = pack2(vv.x, vv.y); o.y = pack2(vv.z, vv.w);
          *(uint2*)((ushort*)out + (size_t)grow * 128 + wn * 64 + seg * 4) = o;
        }
      }
    }
  }
}

// ---------------- MFMA GEMM (input proj): x fp32, same barrier-free structure --

__global__ __launch_bounds__(256, 2)
void gemm_in(const float* __restrict__ X, const ushort* __restrict__ Bfm,
             const float* __restrict__ bias,
             const float* __restrict__ gamma, const float* __restrict__ beta,
             const float* __restrict__ mean, const float* __restrict__ var,
             ushort* __restrict__ out, int N) {
  __shared__ float Cb_all[4 * 16 * 68];
  int tid = threadIdx.x, wave = tid >> 6, lane = tid & 63;
  int wm = wave >> 1, wn = wave & 1, quad = lane >> 4, l16 = lane & 15;
  int m0 = blockIdx.x * 128;

  int rowm[4];
  #pragma unroll
  for (int mt = 0; mt < 4; ++mt) {
    int r = m0 + wm * 64 + mt * 16 + l16;
    rowm[mt] = r < N ? r : N - 1;
  }

  float4 f_buf[2][4][2];
  uint4 b_buf[2][4];
  #pragma unroll
  for (int mt = 0; mt < 4; ++mt) {
    const float* p = X + (size_t)rowm[mt] * 256 + quad * 8;
    f_buf[0][mt][0] = *(const float4*)p;
    f_buf[0][mt][1] = *(const float4*)(p + 4);
  }
  {
    const ushort* bp = Bfm + (size_t)(wn * 4 * 256 + lane) * 8;
    #pragma unroll
    for (int nt = 0; nt < 4; ++nt)
      b_buf[0][nt] = *(const uint4*)(bp + nt * 2048);
  }

  f32x4 acc[4][4] = {};

  #pragma unroll
  for (int kt = 0; kt < 8; ++kt) {
    if (kt < 7) {
      int k1 = kt + 1;
      int ko = k1 * 32 + quad * 8;
      #pragma unroll
      for (int mt = 0; mt < 4; ++mt) {
        const float* p = X + (size_t)rowm[mt] * 256 + ko;
        f_buf[k1 & 1][mt][0] = *(const float4*)p;
        f_buf[k1 & 1][mt][1] = *(const float4*)(p + 4);
      }
      const ushort* bp = Bfm + ((size_t)(k1 >> 2) * 16384 +
                                (size_t)((wn * 4) * 256 + (k1 & 3) * 64 + lane) * 8);
      #pragma unroll
      for (int nt = 0; nt < 4; ++nt)
        b_buf[k1 & 1][nt] = *(const uint4*)(bp + nt * 2048);
    }
    __builtin_amdgcn_sched_barrier(0);
    #pragma unroll
    for (int mt = 0; mt < 4; ++mt) {
      float4 lo = f_buf[kt & 1][mt][0], hi = f_buf[kt & 1][mt][1];
      uint4 av;
      av.x = pack2(lo.x, lo.y); av.y = pack2(lo.z, lo.w);
      av.z = pack2(hi.x, hi.y); av.w = pack2(hi.z, hi.w);
      bf16x8 af = __builtin_bit_cast(bf16x8, av);
      #pragma unroll
      for (int nt = 0; nt < 4; ++nt)
        acc[mt][nt] = __builtin_amdgcn_mfma_f32_16x16x32_bf16(
            af, __builtin_bit_cast(bf16x8, b_buf[kt & 1][nt]), acc[mt][nt], 0, 0, 0);
    }
  }

  #pragma unroll
  for (int nt = 0; nt < 4; ++nt) {
    int c = wn * 64 + nt * 16 + l16;
    float sc = gamma[c] * rsqrtf(var[c] + BN_EPS);
    float sh = beta[c] - mean[c] * sc;
    float bi = bias[c];
    #pragma unroll
    for (int mt = 0; mt < 4; ++mt)
      #pragma unroll
      for (int r = 0; r < 4; ++r)
        acc[mt][nt][r] = fmaxf((acc[mt][nt][r] + bi) * sc + sh, 0.f);
  }

  float* Cb = Cb_all + wave * (16 * 68);
  #pragma unroll
  for (int mt = 0; mt < 4; ++mt) {
    #pragma unroll
    for (int nt = 0; nt < 4; ++nt)
      #pragma unroll
      for (int r = 0; r < 4; ++r)
        Cb[(quad * 4 + r) * 68 + nt * 16 + l16] = acc[mt][nt][r];
    #pragma unroll
    for (int i = 0; i < 4; ++i) {
      int idx = i * 64 + lane, rowl = idx >> 4, seg = idx & 15;
      int grow = m0 + wm * 64 + mt * 16 + rowl;
      if (grow < N) {
        float4 vv = *(float4*)&Cb[rowl * 68 + seg * 4];
        uint2 o;
        o.x = pack2(vv.x, vv.y); o.y = pack2(vv.z, vv.w);
        *(uint2*)(out + (size_t)grow * 128 + wn * 64 + seg * 4) = o;
      }
    }
  }
}

// ---------------- launch ----------------

extern "C" void kernel_launch(void* const* d_in, const int* in_sizes, int n_in,
                              void* d_out, int out_size, void* d_ws, size_t ws_size,
                              hipStream_t stream) {
  const float* x      = (const float*)d_in[0];
  const int*   eidx   = (const int*)d_in[1];
  const float* W_in   = (const float*)d_in[2];
  const float* b_in   = (const float*)d_in[3];
  const float* bng_in = (const float*)d_in[4];
  const float* bnb_in = (const float*)d_in[5];
  const float* bnm_in = (const float*)d_in[6];
  const float* bnv_in = (const float*)d_in[7];
  const float* Wl     = (const float*)d_in[8];
  const float* bl     = (const float*)d_in[9];
  const float* Wr     = (const float*)d_in[10];
  const float* bng    = (const float*)d_in[11];
  const float* bnb    = (const float*)d_in[12];
  const float* bnm    = (const float*)d_in[13];
  const float* bnv    = (const float*)d_in[14];

  const int N = in_sizes[0] / 256;
  const int E = in_sizes[1] / 2;
  const int NB = (N + 255) / 256;
  const int* src = eidx;
  const int* dst = eidx + E;

  char* ws = (char*)d_ws;
  size_t off = 0;
  auto alloc = [&](size_t bytes) {
    void* p = ws + off;
    off = (off + bytes + 255) & ~(size_t)255;
    return p;
  };
  int* cnt      = (int*)alloc((size_t)N * 4);
  int* rowptr   = (int*)alloc((size_t)(N + 1) * 4);
  int* bsum     = (int*)alloc((size_t)NB * 4);
  int* boff     = (int*)alloc((size_t)NB * 4);
  int* col      = (int*)alloc((size_t)E * 4);
  ushort* Bfm   = (ushort*)alloc(4 * 32768 * 2);   // split-K frag-major: [in, l0, l1, l2]
  ushort* hA    = (ushort*)alloc((size_t)N * 128 * 2);
  ushort* hB    = (ushort*)alloc((size_t)N * 128 * 2);
  ushort* agg   = (ushort*)alloc((size_t)N * 128 * 2);
  (void)ws_size; (void)n_in; (void)out_size;

  const int EB = (E + 255) / 256;
  const int GB = (N + 127) / 128;

  // CSR build
  hipMemsetAsync(cnt, 0, (size_t)N * 4, stream);
  hist_kernel<<<EB, 256, 0, stream>>>(dst, cnt, E);
  blocksum_kernel<<<NB, 256, 0, stream>>>(cnt, bsum, N);
  scanbsum_kernel<<<1, 256, 0, stream>>>(bsum, boff, NB, rowptr, N, E);
  writerowptr_kernel<<<NB, 256, 0, stream>>>(cnt, boff, rowptr, N);
  hipMemsetAsync(cnt, 0, (size_t)N * 4, stream);
  fill_kernel<<<EB, 256, 0, stream>>>(src, dst, rowptr, cnt, col, E);

  // weights -> split-K fragment-major bf16
  prep_weights_fm<<<64, 256, 0, stream>>>(W_in, Wl, Wr, Bfm);

  // input projection
  gemm_in<<<GB, 256, 0, stream>>>(x, Bfm, b_in, bng_in, bnb_in, bnm_in, bnv_in, hA, N);

  // 3 SAGE layers: hA -> hB -> hA -> d_out(fp32)
  ushort* hbuf[2] = { hA, hB };
  for (int l = 0; l < 3; ++l) {
    const ushort* h_in = hbuf[l & 1];
    agg_kernel<<<(N + 7) / 8, 256, 0, stream>>>(rowptr, col, h_in, agg, N);
    const ushort* BfmL = Bfm + (size_t)(l + 1) * 32768;
    const float* biasL = bl + l * 128;
    if (l < 2) {
      gemm_layer<false><<<GB, 256, 0, stream>>>(agg, h_in, BfmL, biasL,
          bng + l * 128, bnb + l * 128, bnm + l * 128, bnv + l * 128,
          h_in, (void*)hbuf[(l + 1) & 1], N);
    } else {
      gemm_layer<true><<<GB, 256, 0, stream>>>(agg, h_in, BfmL, biasL,
          bng + l * 128, bnb + l * 128, bnm + l * 128, bnv + l * 128,
          h_in, d_out, N);
    }
  }
}

// Round 6
// 456.156 us; speedup vs baseline: 1.8947x; 1.0503x over previous
//
#include <hip/hip_runtime.h>

#define BN_EPS 1e-5f

typedef __bf16 bf16x8 __attribute__((ext_vector_type(8)));
typedef float f32x4 __attribute__((ext_vector_type(4)));
typedef unsigned int uint;
typedef unsigned short ushort;

__device__ __forceinline__ ushort f2bf(float f) {
  union { float f; uint u; } v; v.f = f;
  uint r = v.u + 0x7FFF + ((v.u >> 16) & 1);   // RNE
  return (ushort)(r >> 16);
}
__device__ __forceinline__ float bf2f_lo(uint u) {
  union { uint i; float f; } v; v.i = u << 16; return v.f;
}
__device__ __forceinline__ float bf2f_hi(uint u) {
  union { uint i; float f; } v; v.i = u & 0xffff0000u; return v.f;
}
__device__ __forceinline__ uint pack2(float a, float b) {
  return (uint)f2bf(a) | ((uint)f2bf(b) << 16);
}

// ---------------- CSR build ----------------

__global__ void hist_kernel(const int* __restrict__ dst, int* __restrict__ cnt, int E) {
  int e = blockIdx.x * 256 + threadIdx.x;
  if (e < E) atomicAdd(&cnt[dst[e]], 1);
}

__device__ __forceinline__ int block_exscan256(int v, int tid, int* ws4) {
  __syncthreads();
  int lane = tid & 63, w = tid >> 6;
  int x = v;
  #pragma unroll
  for (int off = 1; off < 64; off <<= 1) {
    int y = __shfl_up(x, off, 64);
    if (lane >= off) x += y;
  }
  if (lane == 63) ws4[w] = x;
  __syncthreads();
  if (tid == 0) {
    int s = 0;
    for (int i = 0; i < 4; ++i) { int t = ws4[i]; ws4[i] = s; s += t; }
  }
  __syncthreads();
  return ws4[w] + x - v;
}

__global__ void blocksum_kernel(const int* __restrict__ cnt, int* __restrict__ bsum, int N) {
  __shared__ int ws4[4];
  int tid = threadIdx.x;
  int i = blockIdx.x * 256 + tid;
  int v = (i < N) ? cnt[i] : 0;
  #pragma unroll
  for (int off = 32; off > 0; off >>= 1) v += __shfl_down(v, off, 64);
  if ((tid & 63) == 0) ws4[tid >> 6] = v;
  __syncthreads();
  if (tid == 0) bsum[blockIdx.x] = ws4[0] + ws4[1] + ws4[2] + ws4[3];
}

__global__ void scanbsum_kernel(const int* __restrict__ bsum, int* __restrict__ boff,
                                int NB, int* __restrict__ rowptr, int N, int E) {
  __shared__ int ws4[4];
  __shared__ int tot;
  int tid = threadIdx.x;
  int carry = 0;
  for (int base = 0; base < NB; base += 256) {
    int i = base + tid;
    int v = (i < NB) ? bsum[i] : 0;
    int ex = block_exscan256(v, tid, ws4);
    if (i < NB) boff[i] = carry + ex;
    if (tid == 255) tot = ex + v;
    __syncthreads();
    carry += tot;
  }
  if (tid == 0) rowptr[N] = E;
}

__global__ void writerowptr_kernel(const int* __restrict__ cnt, const int* __restrict__ boff,
                                   int* __restrict__ rowptr, int N) {
  __shared__ int ws4[4];
  int tid = threadIdx.x;
  int i = blockIdx.x * 256 + tid;
  int v = (i < N) ? cnt[i] : 0;
  int ex = block_exscan256(v, tid, ws4);
  if (i < N) rowptr[i] = boff[blockIdx.x] + ex;
}

__global__ void fill_kernel(const int* __restrict__ src, const int* __restrict__ dst,
                            const int* __restrict__ rowptr, int* __restrict__ cur,
                            int* __restrict__ col, int E) {
  int e = blockIdx.x * 256 + threadIdx.x;
  if (e < E) {
    int d = dst[e];
    int p = rowptr[d] + atomicAdd(&cur[d], 1);
    col[p] = src[e];
  }
}

// ---------------- weight prep: split-K fragment-major bf16 ----------------
// Piece p: mat = p>>12, rem = p&4095, half = rem>>11, rem2 = rem&2047,
// nt = rem2>>8, kt2 = (rem2>>6)&3, lane = rem2&63.
// Piece = Bt[n = nt*16+(lane&15)][k = (half*4+kt2)*32+(lane>>4)*8 + 0..7].

__global__ void prep_weights_fm(const float* __restrict__ W_in, const float* __restrict__ Wl,
                                const float* __restrict__ Wr, ushort* __restrict__ Bfm) {
  int p = blockIdx.x * 256 + threadIdx.x;
  int mat = p >> 12;
  int rem = p & 4095;
  int half = rem >> 11;
  int rem2 = rem & 2047;
  int nt = rem2 >> 8, kt2 = (rem2 >> 6) & 3, lane = rem2 & 63;
  int n = nt * 16 + (lane & 15);
  int k0 = (half * 4 + kt2) * 32 + (lane >> 4) * 8;
  ushort tmp[8];
  #pragma unroll
  for (int j = 0; j < 8; ++j) {
    int k = k0 + j;
    float v;
    if (mat == 0) v = W_in[k * 128 + n];
    else {
      int l = mat - 1;
      v = (k < 128) ? Wl[l * 16384 + k * 128 + n] : Wr[l * 16384 + (k - 128) * 128 + n];
    }
    tmp[j] = f2bf(v);
  }
  *(uint4*)&Bfm[(size_t)p * 8] = *(const uint4*)tmp;
}

// ---------------- mean aggregation: 2 nodes per wave, deg inline ----------

__global__ void agg_kernel(const int* __restrict__ rowptr, const int* __restrict__ col,
                           const ushort* __restrict__ h, ushort* __restrict__ agg, int N) {
  int node = blockIdx.x * 8 + (threadIdx.x >> 5);
  if (node >= N) return;
  int lane = threadIdx.x & 31;
  const ushort* hp = h + lane * 4;
  int beg = rowptr[node], end = rowptr[node + 1];
  int deg = end - beg;
  float di = 1.0f / (float)(deg > 0 ? deg : 1);
  float a0 = 0.f, a1 = 0.f, a2 = 0.f, a3 = 0.f;
  int e = beg;
  for (; e + 3 < end; e += 4) {
    uint2 v0 = *(const uint2*)(hp + (size_t)col[e] * 128);
    uint2 v1 = *(const uint2*)(hp + (size_t)col[e + 1] * 128);
    uint2 v2 = *(const uint2*)(hp + (size_t)col[e + 2] * 128);
    uint2 v3 = *(const uint2*)(hp + (size_t)col[e + 3] * 128);
    a0 += (bf2f_lo(v0.x) + bf2f_lo(v1.x)) + (bf2f_lo(v2.x) + bf2f_lo(v3.x));
    a1 += (bf2f_hi(v0.x) + bf2f_hi(v1.x)) + (bf2f_hi(v2.x) + bf2f_hi(v3.x));
    a2 += (bf2f_lo(v0.y) + bf2f_lo(v1.y)) + (bf2f_lo(v2.y) + bf2f_lo(v3.y));
    a3 += (bf2f_hi(v0.y) + bf2f_hi(v1.y)) + (bf2f_hi(v2.y) + bf2f_hi(v3.y));
  }
  for (; e < end; ++e) {
    uint2 v0 = *(const uint2*)(hp + (size_t)col[e] * 128);
    a0 += bf2f_lo(v0.x); a1 += bf2f_hi(v0.x);
    a2 += bf2f_lo(v0.y); a3 += bf2f_hi(v0.y);
  }
  uint2 o;
  o.x = pack2(a0 * di, a1 * di);
  o.y = pack2(a2 * di, a3 * di);
  *(uint2*)(agg + (size_t)node * 128 + lane * 4) = o;
}

// ---------------- MFMA GEMM (layers): BM=64, barrier-free ---------------------
// 1563 blocks (~6/CU), 4 waves (2m x 2n), 32x64 per wave. B-frags from L2-hot
// frag-major global; A+B depth-1 double-buffer; per-wave epilogue LDS bounce.

template<bool F32OUT>
__global__ __launch_bounds__(256, 4)
void gemm_layer(const ushort* __restrict__ A0, const ushort* __restrict__ A1,
                const ushort* __restrict__ Bfm, const float* __restrict__ bias,
                const float* __restrict__ gamma, const float* __restrict__ beta,
                const float* __restrict__ mean, const float* __restrict__ var,
                const ushort* __restrict__ residual, void* __restrict__ out, int N) {
  __shared__ float Cb_all[4 * 16 * 68];
  int tid = threadIdx.x, wave = tid >> 6, lane = tid & 63;
  int wm = wave >> 1, wn = wave & 1, quad = lane >> 4, l16 = lane & 15;
  int m0 = blockIdx.x * 64;

  int rowm[2];
  #pragma unroll
  for (int mt = 0; mt < 2; ++mt) {
    int r = m0 + wm * 32 + mt * 16 + l16;
    rowm[mt] = r < N ? r : N - 1;
  }

  uint4 a_buf[2][2], b_buf[2][4];
  #pragma unroll
  for (int mt = 0; mt < 2; ++mt)
    a_buf[0][mt] = *(const uint4*)(A0 + (size_t)rowm[mt] * 128 + quad * 8);
  {
    const ushort* bp = Bfm + (size_t)(wn * 4 * 256 + lane) * 8;
    #pragma unroll
    for (int nt = 0; nt < 4; ++nt)
      b_buf[0][nt] = *(const uint4*)(bp + nt * 2048);
  }

  f32x4 acc[2][4] = {};

  #pragma unroll
  for (int kt = 0; kt < 8; ++kt) {
    if (kt < 7) {
      int k1 = kt + 1;
      const ushort* bse = (k1 < 4) ? A0 : A1;
      int ko = (k1 & 3) * 32 + quad * 8;
      #pragma unroll
      for (int mt = 0; mt < 2; ++mt)
        a_buf[k1 & 1][mt] = *(const uint4*)(bse + (size_t)rowm[mt] * 128 + ko);
      const ushort* bp = Bfm + ((size_t)(k1 >> 2) * 16384 +
                                (size_t)((wn * 4) * 256 + (k1 & 3) * 64 + lane) * 8);
      #pragma unroll
      for (int nt = 0; nt < 4; ++nt)
        b_buf[k1 & 1][nt] = *(const uint4*)(bp + nt * 2048);
    }
    __builtin_amdgcn_sched_barrier(0);   // loads stay issued ahead of the MFMAs
    #pragma unroll
    for (int mt = 0; mt < 2; ++mt) {
      bf16x8 af = __builtin_bit_cast(bf16x8, a_buf[kt & 1][mt]);
      #pragma unroll
      for (int nt = 0; nt < 4; ++nt)
        acc[mt][nt] = __builtin_amdgcn_mfma_f32_16x16x32_bf16(
            af, __builtin_bit_cast(bf16x8, b_buf[kt & 1][nt]), acc[mt][nt], 0, 0, 0);
    }
  }

  // bias + BN + ReLU in registers
  #pragma unroll
  for (int nt = 0; nt < 4; ++nt) {
    int c = wn * 64 + nt * 16 + l16;
    float sc = gamma[c] * rsqrtf(var[c] + BN_EPS);
    float sh = beta[c] - mean[c] * sc;
    float bi = bias[c];
    #pragma unroll
    for (int mt = 0; mt < 2; ++mt)
      #pragma unroll
      for (int r = 0; r < 4; ++r)
        acc[mt][nt][r] = fmaxf((acc[mt][nt][r] + bi) * sc + sh, 0.f);
  }

  // per-wave LDS bounce for vectorized residual+store (no barriers)
  float* Cb = Cb_all + wave * (16 * 68);
  #pragma unroll
  for (int mt = 0; mt < 2; ++mt) {
    #pragma unroll
    for (int nt = 0; nt < 4; ++nt)
      #pragma unroll
      for (int r = 0; r < 4; ++r)
        Cb[(quad * 4 + r) * 68 + nt * 16 + l16] = acc[mt][nt][r];
    #pragma unroll
    for (int i = 0; i < 4; ++i) {
      int idx = i * 64 + lane, rowl = idx >> 4, seg = idx & 15;
      int grow = m0 + wm * 32 + mt * 16 + rowl;
      if (grow < N) {
        float4 vv = *(float4*)&Cb[rowl * 68 + seg * 4];
        uint2 rv = *(const uint2*)(residual + (size_t)grow * 128 + wn * 64 + seg * 4);
        vv.x += bf2f_lo(rv.x); vv.y += bf2f_hi(rv.x);
        vv.z += bf2f_lo(rv.y); vv.w += bf2f_hi(rv.y);
        if (F32OUT) {
          *(float4*)((float*)out + (size_t)grow * 128 + wn * 64 + seg * 4) = vv;
        } else {
          uint2 o;
          o.x = pack2(vv.x, vv.y); o.y = pack2(vv.z, vv.w);
          *(uint2*)((ushort*)out + (size_t)grow * 128 + wn * 64 + seg * 4) = o;
        }
      }
    }
  }
}

// ---------------- MFMA GEMM (input proj): x fp32, BM=64, barrier-free ---------

__global__ __launch_bounds__(256, 4)
void gemm_in(const float* __restrict__ X, const ushort* __restrict__ Bfm,
             const float* __restrict__ bias,
             const float* __restrict__ gamma, const float* __restrict__ beta,
             const float* __restrict__ mean, const float* __restrict__ var,
             ushort* __restrict__ out, int N) {
  __shared__ float Cb_all[4 * 16 * 68];
  int tid = threadIdx.x, wave = tid >> 6, lane = tid & 63;
  int wm = wave >> 1, wn = wave & 1, quad = lane >> 4, l16 = lane & 15;
  int m0 = blockIdx.x * 64;

  int rowm[2];
  #pragma unroll
  for (int mt = 0; mt < 2; ++mt) {
    int r = m0 + wm * 32 + mt * 16 + l16;
    rowm[mt] = r < N ? r : N - 1;
  }

  float4 f_buf[2][2][2];
  uint4 b_buf[2][4];
  #pragma unroll
  for (int mt = 0; mt < 2; ++mt) {
    const float* p = X + (size_t)rowm[mt] * 256 + quad * 8;
    f_buf[0][mt][0] = *(const float4*)p;
    f_buf[0][mt][1] = *(const float4*)(p + 4);
  }
  {
    const ushort* bp = Bfm + (size_t)(wn * 4 * 256 + lane) * 8;
    #pragma unroll
    for (int nt = 0; nt < 4; ++nt)
      b_buf[0][nt] = *(const uint4*)(bp + nt * 2048);
  }

  f32x4 acc[2][4] = {};

  #pragma unroll
  for (int kt = 0; kt < 8; ++kt) {
    if (kt < 7) {
      int k1 = kt + 1;
      int ko = k1 * 32 + quad * 8;
      #pragma unroll
      for (int mt = 0; mt < 2; ++mt) {
        const float* p = X + (size_t)rowm[mt] * 256 + ko;
        f_buf[k1 & 1][mt][0] = *(const float4*)p;
        f_buf[k1 & 1][mt][1] = *(const float4*)(p + 4);
      }
      const ushort* bp = Bfm + ((size_t)(k1 >> 2) * 16384 +
                                (size_t)((wn * 4) * 256 + (k1 & 3) * 64 + lane) * 8);
      #pragma unroll
      for (int nt = 0; nt < 4; ++nt)
        b_buf[k1 & 1][nt] = *(const uint4*)(bp + nt * 2048);
    }
    __builtin_amdgcn_sched_barrier(0);
    #pragma unroll
    for (int mt = 0; mt < 2; ++mt) {
      float4 lo = f_buf[kt & 1][mt][0], hi = f_buf[kt & 1][mt][1];
      uint4 av;
      av.x = pack2(lo.x, lo.y); av.y = pack2(lo.z, lo.w);
      av.z = pack2(hi.x, hi.y); av.w = pack2(hi.z, hi.w);
      bf16x8 af = __builtin_bit_cast(bf16x8, av);
      #pragma unroll
      for (int nt = 0; nt < 4; ++nt)
        acc[mt][nt] = __builtin_amdgcn_mfma_f32_16x16x32_bf16(
            af, __builtin_bit_cast(bf16x8, b_buf[kt & 1][nt]), acc[mt][nt], 0, 0, 0);
    }
  }

  #pragma unroll
  for (int nt = 0; nt < 4; ++nt) {
    int c = wn * 64 + nt * 16 + l16;
    float sc = gamma[c] * rsqrtf(var[c] + BN_EPS);
    float sh = beta[c] - mean[c] * sc;
    float bi = bias[c];
    #pragma unroll
    for (int mt = 0; mt < 2; ++mt)
      #pragma unroll
      for (int r = 0; r < 4; ++r)
        acc[mt][nt][r] = fmaxf((acc[mt][nt][r] + bi) * sc + sh, 0.f);
  }

  float* Cb = Cb_all + wave * (16 * 68);
  #pragma unroll
  for (int mt = 0; mt < 2; ++mt) {
    #pragma unroll
    for (int nt = 0; nt < 4; ++nt)
      #pragma unroll
      for (int r = 0; r < 4; ++r)
        Cb[(quad * 4 + r) * 68 + nt * 16 + l16] = acc[mt][nt][r];
    #pragma unroll
    for (int i = 0; i < 4; ++i) {
      int idx = i * 64 + lane, rowl = idx >> 4, seg = idx & 15;
      int grow = m0 + wm * 32 + mt * 16 + rowl;
      if (grow < N) {
        float4 vv = *(float4*)&Cb[rowl * 68 + seg * 4];
        uint2 o;
        o.x = pack2(vv.x, vv.y); o.y = pack2(vv.z, vv.w);
        *(uint2*)(out + (size_t)grow * 128 + wn * 64 + seg * 4) = o;
      }
    }
  }
}

// ---------------- launch ----------------

extern "C" void kernel_launch(void* const* d_in, const int* in_sizes, int n_in,
                              void* d_out, int out_size, void* d_ws, size_t ws_size,
                              hipStream_t stream) {
  const float* x      = (const float*)d_in[0];
  const int*   eidx   = (const int*)d_in[1];
  const float* W_in   = (const float*)d_in[2];
  const float* b_in   = (const float*)d_in[3];
  const float* bng_in = (const float*)d_in[4];
  const float* bnb_in = (const float*)d_in[5];
  const float* bnm_in = (const float*)d_in[6];
  const float* bnv_in = (const float*)d_in[7];
  const float* Wl     = (const float*)d_in[8];
  const float* bl     = (const float*)d_in[9];
  const float* Wr     = (const float*)d_in[10];
  const float* bng    = (const float*)d_in[11];
  const float* bnb    = (const float*)d_in[12];
  const float* bnm    = (const float*)d_in[13];
  const float* bnv    = (const float*)d_in[14];

  const int N = in_sizes[0] / 256;
  const int E = in_sizes[1] / 2;
  const int NB = (N + 255) / 256;
  const int* src = eidx;
  const int* dst = eidx + E;

  char* ws = (char*)d_ws;
  size_t off = 0;
  auto alloc = [&](size_t bytes) {
    void* p = ws + off;
    off = (off + bytes + 255) & ~(size_t)255;
    return p;
  };
  int* cnt      = (int*)alloc((size_t)N * 4);
  int* rowptr   = (int*)alloc((size_t)(N + 1) * 4);
  int* bsum     = (int*)alloc((size_t)NB * 4);
  int* boff     = (int*)alloc((size_t)NB * 4);
  int* col      = (int*)alloc((size_t)E * 4);
  ushort* Bfm   = (ushort*)alloc(4 * 32768 * 2);   // split-K frag-major: [in, l0, l1, l2]
  ushort* hA    = (ushort*)alloc((size_t)N * 128 * 2);
  ushort* hB    = (ushort*)alloc((size_t)N * 128 * 2);
  ushort* agg   = (ushort*)alloc((size_t)N * 128 * 2);
  (void)ws_size; (void)n_in; (void)out_size;

  const int EB = (E + 255) / 256;
  const int GB = (N + 63) / 64;

  // CSR build
  hipMemsetAsync(cnt, 0, (size_t)N * 4, stream);
  hist_kernel<<<EB, 256, 0, stream>>>(dst, cnt, E);
  blocksum_kernel<<<NB, 256, 0, stream>>>(cnt, bsum, N);
  scanbsum_kernel<<<1, 256, 0, stream>>>(bsum, boff, NB, rowptr, N, E);
  writerowptr_kernel<<<NB, 256, 0, stream>>>(cnt, boff, rowptr, N);
  hipMemsetAsync(cnt, 0, (size_t)N * 4, stream);
  fill_kernel<<<EB, 256, 0, stream>>>(src, dst, rowptr, cnt, col, E);

  // weights -> split-K fragment-major bf16
  prep_weights_fm<<<64, 256, 0, stream>>>(W_in, Wl, Wr, Bfm);

  // input projection
  gemm_in<<<GB, 256, 0, stream>>>(x, Bfm, b_in, bng_in, bnb_in, bnm_in, bnv_in, hA, N);

  // 3 SAGE layers: hA -> hB -> hA -> d_out(fp32)
  ushort* hbuf[2] = { hA, hB };
  for (int l = 0; l < 3; ++l) {
    const ushort* h_in = hbuf[l & 1];
    agg_kernel<<<(N + 7) / 8, 256, 0, stream>>>(rowptr, col, h_in, agg, N);
    const ushort* BfmL = Bfm + (size_t)(l + 1) * 32768;
    const float* biasL = bl + l * 128;
    if (l < 2) {
      gemm_layer<false><<<GB, 256, 0, stream>>>(agg, h_in, BfmL, biasL,
          bng + l * 128, bnb + l * 128, bnm + l * 128, bnv + l * 128,
          h_in, (void*)hbuf[(l + 1) & 1], N);
    } else {
      gemm_layer<true><<<GB, 256, 0, stream>>>(agg, h_in, BfmL, biasL,
          bng + l * 128, bnb + l * 128, bnm + l * 128, bnv + l * 128,
          h_in, d_out, N);
    }
  }
}